// Round 12
// baseline (362.583 us; speedup 1.0000x reference)
//
#include <hip/hip_runtime.h>
#include <hip/hip_cooperative_groups.h>
#include <hip/hip_bf16.h>
#include <math.h>

namespace cg = cooperative_groups;

#define NEG_SLOPE 0.2f

constexpr int BSZ = 8, T = 100, NN = 2048, N = BSZ * NN; // N = 16384
constexpr int CIN = 128, H1 = 4, F1 = 256, F2 = 128;
constexpr int E = 32768;
constexpr int KP = 40;      // padded LDS inner dim (f16)
constexpr int MAXDEG = 64;  // Poisson(16) tail; P(deg>64) ~ 0

typedef _Float16 f16x8 __attribute__((ext_vector_type(8)));
typedef float f32x4 __attribute__((ext_vector_type(4)));

__device__ inline float lrelu(float m) { return m > 0.f ? m : NEG_SLOPE * m; }
__device__ inline float eluf(float v) { return v > 0.f ? v : expm1f(v); }

struct Args {
    const float* in; const int* ei;
    const float *Wt, *bt, *Wl1, *Wr1, *att1, *b1, *Wl2, *Wr2, *att2, *b2;
    float* out;
    _Float16 *xTh, *xh, *h1h;
    float *xl1, *xr1, *xl2, *xr2, *acc2;
    _Float16 *Tt, *T1l, *T1r, *T2l, *T2r;
    int *cnt, *srcs;
};

__global__ __launch_bounds__(512) void mega(Args a) {
    cg::grid_group gg = cg::this_grid();
    const int t = threadIdx.x;
    const int blk = blockIdx.x;              // 256 blocks
    const int wave = t >> 6, lane = t & 63;
    const int quad = lane >> 4, l15 = lane & 15;
    __shared__ __align__(16) char smemraw[40960];

    // ================= P0: zero cnt / init out=b2 / weight transposes / input cvt
    {
        int gid = blk * 512 + t;
        if (gid < NN) a.cnt[gid] = 0;
        else if (gid < NN + BSZ * F2) a.out[gid - NN] = a.b2[(gid - NN) & (F2 - 1)];
        if (blk < 144) {  // weight transpose tiles: Wt 16, Wl1 32, Wr1 32, Wl2 32, Wr2 32
            int job = blk, which, base;
            if (job < 16)       { which = 0; base = 0; }
            else if (job < 48)  { which = 1; base = 16; }
            else if (job < 80)  { which = 2; base = 48; }
            else if (job < 112) { which = 3; base = 80; }
            else                { which = 4; base = 112; }
            const int Ks[5] = {100, 128, 128, 256, 256};
            const int Kd[5] = {128, 128, 128, 256, 256};
            const int Nc[5] = {128, 256, 256, 128, 128};
            const float* Wsrc[5] = {a.Wt, a.Wl1, a.Wr1, a.Wl2, a.Wr2};
            _Float16* Wdst[5] = {a.Tt, a.T1l, a.T1r, a.T2l, a.T2r};
            int rel = job - base;
            int ks = Ks[which], kd = Kd[which], nc = Nc[which];
            int tilesN = nc / 32;
            int tk = (rel / tilesN) * 32, tn = (rel % tilesN) * 32;
            const float* src = Wsrc[which];
            _Float16* dst = Wdst[which];
            _Float16 (*tile)[33] = (_Float16(*)[33])smemraw;
            int tx = t & 31, ty = t >> 5;      // ty 0..15
            for (int r = ty; r < 32; r += 16)
                tile[r][tx] = (tk + r < ks) ? (_Float16)src[(tk + r) * nc + tn + tx] : (_Float16)0.f;
            __syncthreads();
            for (int r = ty; r < 32; r += 16)
                dst[(tn + r) * kd + tk + tx] = tile[tx][r];
        }
        __syncthreads();
        {   // input transpose+f16: 256 jobs, 1/block: [100 x 64] tile
            float* lt = (float*)smemraw;       // 100*65*4 = 26 KB
            int b = blk >> 5, node0 = (blk & 31) * 64;
            for (int i = t; i < T * 64; i += 512) {
                int tk2 = i >> 6, n = i & 63;
                lt[tk2 * 65 + n] = a.in[(b * T + tk2) * NN + node0 + n];
            }
            __syncthreads();
            int node = t >> 3, seg = t & 7;    // 64 nodes x 8 segs x 16 k
            _Float16* dst = &a.xTh[(size_t)(b * NN + node0 + node) * 128 + seg * 16];
            #pragma unroll
            for (int j = 0; j < 2; ++j) {
                f16x8 v;
                #pragma unroll
                for (int e = 0; e < 8; ++e) {
                    int k = seg * 16 + j * 8 + e;
                    v[e] = (k < T) ? (_Float16)lt[k * 65 + node] : (_Float16)0.f;
                }
                *(f16x8*)&dst[j * 8] = v;
            }
        }
    }
    gg.sync();

    // ================= P1: edge hist + slot scatter ; temb MFMA GEMM (2 teams/block)
    {
        int gid = blk * 512 + t;
        if (gid < E) {
            int d = a.ei[E + gid];
            int slot = atomicAdd(&a.cnt[d], 1);
            a.srcs[d * MAXDEG + slot] = a.ei[gid];
        }
        int team = t >> 8, tt = t & 255;
        int job = blk * 2 + team;              // 512 jobs of 32 rows
        _Float16* bs = (_Float16*)smemraw + team * (128 * KP);   // 10 KB/team
        int w4 = tt >> 6, ln = tt & 63, qd = ln >> 4, l5 = ln & 15;
        int row0 = job * 32;
        f32x4 acc[2][2];
        #pragma unroll
        for (int s = 0; s < 2; ++s)
            #pragma unroll
            for (int c = 0; c < 2; ++c) acc[s][c] = (f32x4){0,0,0,0};
        for (int kt = 0; kt < 128; kt += 32) {
            if (kt) __syncthreads();
            #pragma unroll
            for (int it = 0; it < 2; ++it) {
                int idx = tt + it * 256;
                int col = idx >> 2, j = idx & 3;
                *(f16x8*)&bs[col * KP + j * 8] = *(const f16x8*)&a.Tt[col * 128 + kt + j * 8];
            }
            __syncthreads();
            f16x8 af0 = *(const f16x8*)&a.xTh[(size_t)(row0 + l5) * 128 + kt + qd * 8];
            f16x8 af1 = *(const f16x8*)&a.xTh[(size_t)(row0 + 16 + l5) * 128 + kt + qd * 8];
            #pragma unroll
            for (int ct = 0; ct < 2; ++ct) {
                int col = w4 * 32 + ct * 16 + l5;
                f16x8 bf = *(const f16x8*)&bs[col * KP + qd * 8];
                acc[0][ct] = __builtin_amdgcn_mfma_f32_16x16x32_f16(af0, bf, acc[0][ct], 0, 0, 0);
                acc[1][ct] = __builtin_amdgcn_mfma_f32_16x16x32_f16(af1, bf, acc[1][ct], 0, 0, 0);
            }
        }
        #pragma unroll
        for (int ct = 0; ct < 2; ++ct) {
            int col = w4 * 32 + ct * 16 + l5;
            float bv = a.bt[col];
            #pragma unroll
            for (int s = 0; s < 2; ++s)
                #pragma unroll
                for (int r = 0; r < 4; ++r)
                    a.xh[(size_t)(row0 + s * 16 + qd * 4 + r) * CIN + col] =
                        (_Float16)(acc[s][ct][r] + bv);
        }
    }
    gg.sync();

    // ================= P2: layer-1 dual MFMA GEMM, 2 sequential 32-row jobs/block
    for (int job = blk; job < 512; job += 256) {
        _Float16* bs = (_Float16*)smemraw;     // 40 KB
        const int mat = wave >> 2, cg4 = wave & 3;
        const int row0 = job * 32;
        const int nmats = (row0 < NN) ? 2 : 1;
        f32x4 acc[2][4];
        #pragma unroll
        for (int s = 0; s < 2; ++s)
            #pragma unroll
            for (int c = 0; c < 4; ++c) acc[s][c] = (f32x4){0,0,0,0};
        for (int kt = 0; kt < CIN; kt += 32) {
            if (kt) __syncthreads();
            for (int it = 0; it < nmats * 2; ++it) {
                int idx = t + it * 512;
                int m = idx >> 10, rem = idx & 1023;
                int col = rem >> 2, j = rem & 3;
                const _Float16* src = (m ? a.T1r : a.T1l) + col * CIN + kt + j * 8;
                *(f16x8*)&bs[(m * 256 + col) * KP + j * 8] = *(const f16x8*)src;
            }
            __syncthreads();
            if (mat < nmats) {
                f16x8 af0 = *(const f16x8*)&a.xh[(size_t)(row0 + l15) * CIN + kt + quad * 8];
                f16x8 af1 = *(const f16x8*)&a.xh[(size_t)(row0 + 16 + l15) * CIN + kt + quad * 8];
                #pragma unroll
                for (int ct = 0; ct < 4; ++ct) {
                    int col = cg4 * 64 + ct * 16 + l15;
                    f16x8 bf = *(const f16x8*)&bs[(mat * 256 + col) * KP + quad * 8];
                    acc[0][ct] = __builtin_amdgcn_mfma_f32_16x16x32_f16(af0, bf, acc[0][ct], 0, 0, 0);
                    acc[1][ct] = __builtin_amdgcn_mfma_f32_16x16x32_f16(af1, bf, acc[1][ct], 0, 0, 0);
                }
            }
        }
        if (row0 < NN) {
            float* dst = mat ? a.xr1 : a.xl1;
            #pragma unroll
            for (int s = 0; s < 2; ++s)
                #pragma unroll
                for (int ct = 0; ct < 4; ++ct) {
                    int col = cg4 * 64 + ct * 16 + l15;
                    #pragma unroll
                    for (int r = 0; r < 4; ++r)
                        dst[(row0 + s * 16 + quad * 4 + r) * F1 + col] = acc[s][ct][r];
                }
        } else if (mat == 0) {  // self-only rows: h1 = elu(xl + b1) directly
            #pragma unroll
            for (int ct = 0; ct < 4; ++ct) {
                int col = cg4 * 64 + ct * 16 + l15;
                float bv = a.b1[col];
                #pragma unroll
                for (int s = 0; s < 2; ++s)
                    #pragma unroll
                    for (int r = 0; r < 4; ++r)
                        a.h1h[(size_t)(row0 + s * 16 + quad * 4 + r) * F1 + col] =
                            (_Float16)eluf(acc[s][ct][r] + bv);
            }
        }
        __syncthreads();
    }
    gg.sync();

    // ================= P3: gather layer 1, one node per wave (2048 waves)
    {
        const int d = blk * 8 + wave;
        const int c = lane;
        float b[4], at[4], sh[4], accv[4] = {0,0,0,0}, dnl[4] = {0,0,0,0};
        #pragma unroll
        for (int k = 0; k < 4; ++k) {
            b[k]  = a.xr1[d * F1 + c + 64 * k];
            at[k] = a.att1[c + 64 * k];
            sh[k] = lrelu(a.xl1[d * F1 + c + 64 * k] + b[k]) * at[k];
        }
        #pragma unroll
        for (int o = 32; o; o >>= 1) {
            #pragma unroll
            for (int k = 0; k < 4; ++k) sh[k] += __shfl_xor(sh[k], o, 64);
        }
        const int deg = a.cnt[d];
        for (int e = 0; e < deg; ++e) {
            int s = a.srcs[d * MAXDEG + e];
            float av[4], p[4];
            #pragma unroll
            for (int k = 0; k < 4; ++k) {
                av[k] = a.xl1[s * F1 + c + 64 * k];
                p[k] = lrelu(av[k] + b[k]) * at[k];
            }
            #pragma unroll
            for (int o = 32; o; o >>= 1) {
                #pragma unroll
                for (int k = 0; k < 4; ++k) p[k] += __shfl_xor(p[k], o, 64);
            }
            #pragma unroll
            for (int k = 0; k < 4; ++k) {
                float w = 8.0f * __expf(p[k] - sh[k]);
                dnl[k] += w;
                accv[k] = fmaf(w, av[k], accv[k]);
            }
        }
        #pragma unroll
        for (int k = 0; k < 4; ++k) {
            int f = c + 64 * k;
            float tot = a.xl1[d * F1 + f] + accv[k];
            a.h1h[d * F1 + f] = (_Float16)eluf(tot / (1.0f + dnl[k] + 1e-16f) + a.b1[f]);
        }
    }
    gg.sync();

    // ================= P4: layer-2 dual MFMA GEMM, 2 sequential jobs/block
    for (int job = blk; job < 512; job += 256) {
        _Float16* bs = (_Float16*)smemraw;     // 20 KB
        const int mat = wave >> 2, cg4 = wave & 3;
        const int row0 = job * 32;
        const int nmats = (row0 < NN) ? 2 : 1;
        f32x4 acc[2][2];
        #pragma unroll
        for (int s = 0; s < 2; ++s)
            #pragma unroll
            for (int c = 0; c < 2; ++c) acc[s][c] = (f32x4){0,0,0,0};
        for (int kt = 0; kt < F1; kt += 32) {
            if (kt) __syncthreads();
            for (int it = 0; it < nmats; ++it) {
                int idx = t + it * 512;
                int m = idx >> 9, rem = idx & 511;
                int col = rem >> 2, j = rem & 3;
                const _Float16* src = (m ? a.T2r : a.T2l) + col * F1 + kt + j * 8;
                *(f16x8*)&bs[(m * 128 + col) * KP + j * 8] = *(const f16x8*)src;
            }
            __syncthreads();
            if (mat < nmats) {
                f16x8 af0 = *(const f16x8*)&a.h1h[(size_t)(row0 + l15) * F1 + kt + quad * 8];
                f16x8 af1 = *(const f16x8*)&a.h1h[(size_t)(row0 + 16 + l15) * F1 + kt + quad * 8];
                #pragma unroll
                for (int ct = 0; ct < 2; ++ct) {
                    int col = cg4 * 32 + ct * 16 + l15;
                    f16x8 bf = *(const f16x8*)&bs[(mat * 128 + col) * KP + quad * 8];
                    acc[0][ct] = __builtin_amdgcn_mfma_f32_16x16x32_f16(af0, bf, acc[0][ct], 0, 0, 0);
                    acc[1][ct] = __builtin_amdgcn_mfma_f32_16x16x32_f16(af1, bf, acc[1][ct], 0, 0, 0);
                }
            }
        }
        if (row0 < NN) {
            float* dst = mat ? a.xr2 : a.xl2;
            #pragma unroll
            for (int s = 0; s < 2; ++s)
                #pragma unroll
                for (int ct = 0; ct < 2; ++ct) {
                    int col = cg4 * 32 + ct * 16 + l15;
                    #pragma unroll
                    for (int r = 0; r < 4; ++r)
                        dst[(row0 + s * 16 + quad * 4 + r) * F2 + col] = acc[s][ct][r];
                }
        } else if (mat == 0) {  // self-only rows: final value (dn = 1)
            #pragma unroll
            for (int s = 0; s < 2; ++s)
                #pragma unroll
                for (int ct = 0; ct < 2; ++ct) {
                    int col = cg4 * 32 + ct * 16 + l15;
                    #pragma unroll
                    for (int r = 0; r < 4; ++r)
                        a.acc2[(size_t)(row0 + s * 16 + quad * 4 + r) * F2 + col] = acc[s][ct][r];
                }
        }
        __syncthreads();
    }
    gg.sync();

    // ================= P5: gather layer 2, one node per wave
    {
        const int d = blk * 8 + wave;
        const int c = lane;
        float b0 = a.xr2[d * F2 + c], b1v = a.xr2[d * F2 + c + 64];
        float at0 = a.att2[c], at1 = a.att2[c + 64];
        float x0 = a.xl2[d * F2 + c], x1 = a.xl2[d * F2 + c + 64];
        float sh = lrelu(x0 + b0) * at0 + lrelu(x1 + b1v) * at1;
        #pragma unroll
        for (int o = 32; o; o >>= 1) sh += __shfl_xor(sh, o, 64);
        float acc0 = 0.f, acc1v = 0.f, dnl = 0.f;
        const int deg = a.cnt[d];
        for (int e = 0; e < deg; ++e) {
            int s = a.srcs[d * MAXDEG + e];
            float a0 = a.xl2[s * F2 + c], a1 = a.xl2[s * F2 + c + 64];
            float p = lrelu(a0 + b0) * at0 + lrelu(a1 + b1v) * at1;
            #pragma unroll
            for (int o = 32; o; o >>= 1) p += __shfl_xor(p, o, 64);
            float w = 8.0f * __expf(p - sh);
            dnl += w;
            acc0 = fmaf(w, a0, acc0);
            acc1v = fmaf(w, a1, acc1v);
        }
        float dnf = 1.0f + dnl + 1e-16f;
        a.acc2[d * F2 + c]      = (x0 + acc0) / dnf;
        a.acc2[d * F2 + c + 64] = (x1 + acc1v) / dnf;
    }
    gg.sync();

    // ================= P6: batched mean into out (out pre-seeded with b2)
    {
        int team = t >> 8, tt = t & 255;
        int job = blk * 2 + team;              // 512 jobs: 8 batches x 64 chunks of 32 nodes
        if (tt < F2) {
            int b = job >> 6;
            int n0 = b * NN + (job & 63) * 32;
            float s = 0.f;
            for (int i = 0; i < 32; ++i) s += a.acc2[(size_t)(n0 + i) * F2 + tt];
            atomicAdd(&a.out[b * F2 + tt], s * (1.0f / NN));
        }
    }
}

extern "C" void kernel_launch(void* const* d_in, const int* in_sizes, int n_in,
                              void* d_out, int out_size, void* d_ws, size_t ws_size,
                              hipStream_t stream) {
    Args a;
    a.in   = (const float*)d_in[0];
    a.ei   = (const int*)d_in[1];
    a.Wt   = (const float*)d_in[2];
    a.bt   = (const float*)d_in[3];
    a.Wl1  = (const float*)d_in[4];
    a.Wr1  = (const float*)d_in[5];
    a.att1 = (const float*)d_in[6];
    a.b1   = (const float*)d_in[7];
    a.Wl2  = (const float*)d_in[8];
    a.Wr2  = (const float*)d_in[9];
    a.att2 = (const float*)d_in[10];
    a.b2   = (const float*)d_in[11];
    a.out  = (float*)d_out;

    float* ws = (float*)d_ws;
    a.xTh  = (_Float16*)ws;                 // N*128 f16
    a.xh   = a.xTh + (size_t)N * 128;       // N*128 f16
    a.h1h  = a.xh + (size_t)N * CIN;        // N*256 f16
    a.xl1  = (float*)(a.h1h + (size_t)N * F1);  // NN*F1
    a.xr1  = a.xl1 + NN * F1;               // NN*F1
    a.xl2  = a.xr1 + NN * F1;               // NN*F2
    a.xr2  = a.xl2 + NN * F2;               // NN*F2
    a.acc2 = a.xr2 + NN * F2;               // N*F2
    a.Tt   = (_Float16*)(a.acc2 + (size_t)N * F2);  // 128*128
    a.T1l  = a.Tt + 128 * 128;              // 256*128
    a.T1r  = a.T1l + 256 * 128;
    a.T2l  = a.T1r + 256 * 128;             // 128*256
    a.T2r  = a.T2l + 128 * 256;
    a.cnt  = (int*)(a.T2r + 128 * 256);     // NN
    a.srcs = a.cnt + NN;                    // NN*64

    void* kargs[] = { &a };
    hipLaunchCooperativeKernel((void*)mega, dim3(256), dim3(512), kargs, 0, stream);
}

// Round 13
// 190.511 us; speedup vs baseline: 1.9032x; 1.9032x over previous
//
#include <hip/hip_runtime.h>
#include <hip/hip_bf16.h>
#include <math.h>

#define NEG_SLOPE 0.2f

constexpr int BSZ = 8, T = 100, NN = 2048, N = BSZ * NN; // N = 16384
constexpr int CIN = 128, F1 = 256, F2 = 128;
constexpr int E = 32768;
constexpr int KP = 40;      // padded LDS inner dim (f16) for 32-k tiles
constexpr int MAXDEG = 64;

typedef _Float16 f16x8 __attribute__((ext_vector_type(8)));
typedef float f32x4 __attribute__((ext_vector_type(4)));

__device__ inline float lrelu(float m) { return m > 0.f ? m : NEG_SLOPE * m; }
__device__ inline float eluf(float v) { return v > 0.f ? v : expm1f(v); }

// ===== D1: weight transposes (+f16, +K-pad) ; zero cnt ; out = b2 =====
__global__ __launch_bounds__(256) void k_prep(const float* __restrict__ Wt,
        const float* __restrict__ Wl1, const float* __restrict__ Wr1,
        const float* __restrict__ Wl2, const float* __restrict__ Wr2,
        const float* __restrict__ b2,
        _Float16* __restrict__ Tt, _Float16* __restrict__ T1l,
        _Float16* __restrict__ T1r, _Float16* __restrict__ T2l,
        _Float16* __restrict__ T2r, int* __restrict__ cnt, float* __restrict__ out) {
    const int job = blockIdx.x;
    const int t = threadIdx.x;
    if (job == 144) {
        for (int i = t; i < NN; i += 256) cnt[i] = 0;
        for (int i = t; i < BSZ * F2; i += 256) out[i] = b2[i & (F2 - 1)];
        return;
    }
    int which, base;
    if (job < 16)       { which = 0; base = 0; }
    else if (job < 48)  { which = 1; base = 16; }
    else if (job < 80)  { which = 2; base = 48; }
    else if (job < 112) { which = 3; base = 80; }
    else                { which = 4; base = 112; }
    const int Ks[5] = {100, 128, 128, 256, 256};
    const int Kd[5] = {128, 128, 128, 256, 256};
    const int Nc[5] = {128, 256, 256, 128, 128};
    const float* Wsrc[5] = {Wt, Wl1, Wr1, Wl2, Wr2};
    _Float16* Wdst[5] = {Tt, T1l, T1r, T2l, T2r};
    int rel = job - base;
    int ks = Ks[which], kd = Kd[which], nc = Nc[which];
    int tilesN = nc / 32;
    int tk = (rel / tilesN) * 32, tn = (rel % tilesN) * 32;
    const float* src = Wsrc[which];
    _Float16* dst = Wdst[which];
    __shared__ _Float16 tile[32][33];
    int tx = t & 31, ty = t >> 5;
    for (int r = ty; r < 32; r += 8)
        tile[r][tx] = (tk + r < ks) ? (_Float16)src[(tk + r) * nc + tn + tx] : (_Float16)0.f;
    __syncthreads();
    for (int r = ty; r < 32; r += 8)
        dst[(tn + r) * kd + tk + tx] = tile[tx][r];
}

// ===== D2: input transpose+f16 (blocks 0..255) ; hist + slot scatter (256..383) =====
__global__ __launch_bounds__(256) void k_cvt_scat(const float* __restrict__ in,
        _Float16* __restrict__ xTh, const int* __restrict__ ei,
        int* __restrict__ cnt, int* __restrict__ srcs) {
    const int t = threadIdx.x;
    const int blk = blockIdx.x;
    if (blk >= 256) {
        int i = (blk - 256) * 256 + t;          // 128 blocks x 256 = E
        int d = ei[E + i];
        int slot = atomicAdd(&cnt[d], 1);
        if (slot < MAXDEG) srcs[d * MAXDEG + slot] = ei[i];
        return;
    }
    __shared__ float lt[T * 65];
    const int b = blk >> 5, node0 = (blk & 31) * 64;
    for (int i = t; i < T * 64; i += 256) {
        int tt = i >> 6, n = i & 63;
        lt[tt * 65 + n] = in[(b * T + tt) * NN + node0 + n];
    }
    __syncthreads();
    const int node = t >> 2, seg = t & 3;
    _Float16* dst = &xTh[(size_t)(b * NN + node0 + node) * 128 + seg * 32];
    #pragma unroll
    for (int j = 0; j < 4; ++j) {
        f16x8 v;
        #pragma unroll
        for (int e = 0; e < 8; ++e) {
            int k = seg * 32 + j * 8 + e;
            v[e] = (k < T) ? (_Float16)lt[k * 65 + node] : (_Float16)0.f;
        }
        *(f16x8*)&dst[j * 8] = v;
    }
}

// ===== D3: fused temb GEMM (xh tile in LDS) + layer-1 dual GEMM =====
// rows<NN -> xl1/xr1 fp32; rows>=NN -> h1h = f16 elu(aL + b1)
__global__ __launch_bounds__(512) void k_gm1f(const _Float16* __restrict__ xTh,
        const _Float16* __restrict__ Tt, const float* __restrict__ bt,
        const _Float16* __restrict__ T1l, const _Float16* __restrict__ T1r,
        const float* __restrict__ b1,
        float* __restrict__ xl1, float* __restrict__ xr1, _Float16* __restrict__ h1h) {
    __shared__ __align__(16) char smem[8704 + 40960];
    _Float16* xt  = (_Float16*)smem;            // [32][136] f16 = 8704 B
    _Float16* stg = (_Float16*)(smem + 8704);   // staging, 40960 B
    const int t = threadIdx.x;
    const int wave = t >> 6, lane = t & 63;
    const int quad = lane >> 4, l15 = lane & 15;
    const int row0 = blockIdx.x * 32;
    // --- Phase A: temb GEMM, out tile -> LDS xt
    #pragma unroll
    for (int it = 0; it < 4; ++it) {            // stage Tt [128][128] -> [128][136]
        int idx = t + it * 512;
        int col = idx >> 4, j = idx & 15;
        *(f16x8*)&stg[col * 136 + j * 8] = *(const f16x8*)&Tt[col * 128 + j * 8];
    }
    __syncthreads();
    {
        const int wcol = wave * 16 + l15;       // 8 waves x 16 = 128 cols
        f32x4 a0 = {0,0,0,0}, a1 = {0,0,0,0};
        #pragma unroll
        for (int kt = 0; kt < 128; kt += 32) {
            f16x8 af0 = *(const f16x8*)&xTh[(size_t)(row0 + l15) * 128 + kt + quad * 8];
            f16x8 af1 = *(const f16x8*)&xTh[(size_t)(row0 + 16 + l15) * 128 + kt + quad * 8];
            f16x8 bf  = *(const f16x8*)&stg[wcol * 136 + kt + quad * 8];
            a0 = __builtin_amdgcn_mfma_f32_16x16x32_f16(af0, bf, a0, 0, 0, 0);
            a1 = __builtin_amdgcn_mfma_f32_16x16x32_f16(af1, bf, a1, 0, 0, 0);
        }
        float bv = bt[wcol];
        #pragma unroll
        for (int r = 0; r < 4; ++r) {
            xt[(quad * 4 + r) * 136 + wcol]      = (_Float16)(a0[r] + bv);
            xt[(16 + quad * 4 + r) * 136 + wcol] = (_Float16)(a1[r] + bv);
        }
    }
    __syncthreads();
    // --- Phase B: layer-1 dual GEMM, A from LDS xt
    const int mat = wave >> 2, cg4 = wave & 3;
    const int nmats = (row0 < NN) ? 2 : 1;
    f32x4 acc[2][4];
    #pragma unroll
    for (int s = 0; s < 2; ++s)
        #pragma unroll
        for (int c = 0; c < 4; ++c) acc[s][c] = (f32x4){0,0,0,0};
    for (int kt = 0; kt < CIN; kt += 32) {
        if (kt) __syncthreads();
        for (int it = 0; it < nmats * 2; ++it) {   // nmats x 256 cols x 4 chunks
            int idx = t + it * 512;
            int m = idx >> 10, rem = idx & 1023;
            int col = rem >> 2, j = rem & 3;
            const _Float16* src = (m ? T1r : T1l) + col * CIN + kt + j * 8;
            *(f16x8*)&stg[(m * 256 + col) * KP + j * 8] = *(const f16x8*)src;
        }
        __syncthreads();
        f16x8 af0 = *(const f16x8*)&xt[l15 * 136 + kt + quad * 8];
        f16x8 af1 = *(const f16x8*)&xt[(16 + l15) * 136 + kt + quad * 8];
        if (mat < nmats) {
            #pragma unroll
            for (int ct = 0; ct < 4; ++ct) {
                int col = cg4 * 64 + ct * 16 + l15;
                f16x8 bf = *(const f16x8*)&stg[(mat * 256 + col) * KP + quad * 8];
                acc[0][ct] = __builtin_amdgcn_mfma_f32_16x16x32_f16(af0, bf, acc[0][ct], 0, 0, 0);
                acc[1][ct] = __builtin_amdgcn_mfma_f32_16x16x32_f16(af1, bf, acc[1][ct], 0, 0, 0);
            }
        }
    }
    if (row0 < NN) {
        float* dst = mat ? xr1 : xl1;
        #pragma unroll
        for (int s = 0; s < 2; ++s)
            #pragma unroll
            for (int ct = 0; ct < 4; ++ct) {
                int col = cg4 * 64 + ct * 16 + l15;
                #pragma unroll
                for (int r = 0; r < 4; ++r)
                    dst[(row0 + s * 16 + quad * 4 + r) * F1 + col] = acc[s][ct][r];
            }
    } else if (mat == 0) {
        #pragma unroll
        for (int ct = 0; ct < 4; ++ct) {
            int col = cg4 * 64 + ct * 16 + l15;
            float bv = b1[col];
            #pragma unroll
            for (int s = 0; s < 2; ++s)
                #pragma unroll
                for (int r = 0; r < 4; ++r)
                    h1h[(size_t)(row0 + s * 16 + quad * 4 + r) * F1 + col] =
                        (_Float16)eluf(acc[s][ct][r] + bv);
        }
    }
}

// ===== D4: fused gather-1 (blocks<64: 32 nodes -> LDS A-tile) + layer-2 dual GEMM =====
// rows<NN -> xl2/xr2; rows>=NN -> fused batch-mean atomicAdd into out (batches 1..7)
__global__ __launch_bounds__(512) void k_g1gm2(const int* __restrict__ cnt,
        const int* __restrict__ srcs, const float* __restrict__ xl1,
        const float* __restrict__ xr1, const float* __restrict__ att1,
        const float* __restrict__ b1, const _Float16* __restrict__ h1h,
        const _Float16* __restrict__ T2l, const _Float16* __restrict__ T2r,
        float* __restrict__ xl2, float* __restrict__ xr2, float* __restrict__ out) {
    __shared__ __align__(16) _Float16 at[32 * 264];   // 16896 B
    __shared__ __align__(16) _Float16 bs[2 * 128 * KP]; // 20480 B
    const int t = threadIdx.x;
    const int wave = t >> 6, lane = t & 63;
    const int quad = lane >> 4, l15 = lane & 15;
    const int row0 = blockIdx.x * 32;
    const bool isLoc = row0 < NN;
    if (isLoc) {   // gather phase: 4 rounds x 8 waves = 32 nodes
        const int c = lane;
        for (int rd = 0; rd < 4; ++rd) {
            const int d = row0 + rd * 8 + wave;
            float b[4], atv[4], sh[4], accv[4] = {0,0,0,0}, dnl[4] = {0,0,0,0};
            #pragma unroll
            for (int k = 0; k < 4; ++k) {
                b[k]   = xr1[d * F1 + c + 64 * k];
                atv[k] = att1[c + 64 * k];
                sh[k]  = lrelu(xl1[d * F1 + c + 64 * k] + b[k]) * atv[k];
            }
            #pragma unroll
            for (int o = 32; o; o >>= 1) {
                #pragma unroll
                for (int k = 0; k < 4; ++k) sh[k] += __shfl_xor(sh[k], o, 64);
            }
            int deg = cnt[d]; deg = deg < MAXDEG ? deg : MAXDEG;
            for (int e = 0; e < deg; ++e) {
                int s = srcs[d * MAXDEG + e];
                float av[4], p[4];
                #pragma unroll
                for (int k = 0; k < 4; ++k) {
                    av[k] = xl1[s * F1 + c + 64 * k];
                    p[k] = lrelu(av[k] + b[k]) * atv[k];
                }
                #pragma unroll
                for (int o = 32; o; o >>= 1) {
                    #pragma unroll
                    for (int k = 0; k < 4; ++k) p[k] += __shfl_xor(p[k], o, 64);
                }
                #pragma unroll
                for (int k = 0; k < 4; ++k) {
                    float w = 8.0f * __expf(p[k] - sh[k]);
                    dnl[k] += w;
                    accv[k] = fmaf(w, av[k], accv[k]);
                }
            }
            #pragma unroll
            for (int k = 0; k < 4; ++k) {
                int f = c + 64 * k;
                float tot = xl1[d * F1 + f] + accv[k];
                at[(rd * 8 + wave) * 264 + f] =
                    (_Float16)eluf(tot / (1.0f + dnl[k] + 1e-16f) + b1[f]);
            }
        }
    }
    __syncthreads();
    // GEMM phase
    const int mat = wave >> 2, cg4 = wave & 3;
    const int nmats = isLoc ? 2 : 1;
    f32x4 acc[2][2];
    #pragma unroll
    for (int s = 0; s < 2; ++s)
        #pragma unroll
        for (int c = 0; c < 2; ++c) acc[s][c] = (f32x4){0,0,0,0};
    for (int kt = 0; kt < F1; kt += 32) {
        if (kt) __syncthreads();
        for (int it = 0; it < nmats; ++it) {
            int idx = t + it * 512;
            int m = idx >> 9, rem = idx & 511;
            int col = rem >> 2, j = rem & 3;
            const _Float16* src = (m ? T2r : T2l) + col * F1 + kt + j * 8;
            *(f16x8*)&bs[(m * 128 + col) * KP + j * 8] = *(const f16x8*)src;
        }
        __syncthreads();
        f16x8 af0, af1;
        if (isLoc) {
            af0 = *(const f16x8*)&at[l15 * 264 + kt + quad * 8];
            af1 = *(const f16x8*)&at[(16 + l15) * 264 + kt + quad * 8];
        } else {
            af0 = *(const f16x8*)&h1h[(size_t)(row0 + l15) * F1 + kt + quad * 8];
            af1 = *(const f16x8*)&h1h[(size_t)(row0 + 16 + l15) * F1 + kt + quad * 8];
        }
        if (mat < nmats) {
            #pragma unroll
            for (int ct = 0; ct < 2; ++ct) {
                int col = cg4 * 32 + ct * 16 + l15;
                f16x8 bf = *(const f16x8*)&bs[(mat * 128 + col) * KP + quad * 8];
                acc[0][ct] = __builtin_amdgcn_mfma_f32_16x16x32_f16(af0, bf, acc[0][ct], 0, 0, 0);
                acc[1][ct] = __builtin_amdgcn_mfma_f32_16x16x32_f16(af1, bf, acc[1][ct], 0, 0, 0);
            }
        }
    }
    if (isLoc) {
        float* dst = mat ? xr2 : xl2;
        #pragma unroll
        for (int s = 0; s < 2; ++s)
            #pragma unroll
            for (int ct = 0; ct < 2; ++ct) {
                int col = cg4 * 32 + ct * 16 + l15;
                #pragma unroll
                for (int r = 0; r < 4; ++r)
                    dst[(row0 + s * 16 + quad * 4 + r) * F2 + col] = acc[s][ct][r];
            }
    } else if (mat == 0) {
        // self rows: value is final (dn=1); fuse batch-mean accumulation
        int b = row0 >> 11;
        #pragma unroll
        for (int ct = 0; ct < 2; ++ct) {
            float s8 = 0.f;
            #pragma unroll
            for (int s = 0; s < 2; ++s)
                #pragma unroll
                for (int r = 0; r < 4; ++r) s8 += acc[s][ct][r];
            s8 += __shfl_xor(s8, 16, 64);
            s8 += __shfl_xor(s8, 32, 64);
            if (quad == 0)
                atomicAdd(&out[b * F2 + cg4 * 32 + ct * 16 + l15], s8 * (1.0f / NN));
        }
    }
}

// ===== D5: gather layer 2 (1 node/wave) + fused batch-0 mean =====
__global__ __launch_bounds__(512) void k_g2out(const int* __restrict__ cnt,
        const int* __restrict__ srcs, const float* __restrict__ xl2,
        const float* __restrict__ xr2, const float* __restrict__ att2,
        float* __restrict__ out) {
    const int t = threadIdx.x;
    const int wave = t >> 6, c = t & 63;
    const int d = blockIdx.x * 8 + wave;    // 0..2047, all batch 0
    float b0 = xr2[d * F2 + c], b1v = xr2[d * F2 + c + 64];
    float at0 = att2[c], at1 = att2[c + 64];
    float x0 = xl2[d * F2 + c], x1 = xl2[d * F2 + c + 64];
    float sh = lrelu(x0 + b0) * at0 + lrelu(x1 + b1v) * at1;
    #pragma unroll
    for (int o = 32; o; o >>= 1) sh += __shfl_xor(sh, o, 64);
    float acc0 = 0.f, acc1v = 0.f, dnl = 0.f;
    int deg = cnt[d]; deg = deg < MAXDEG ? deg : MAXDEG;
    for (int e = 0; e < deg; ++e) {
        int s = srcs[d * MAXDEG + e];
        float a0 = xl2[s * F2 + c], a1 = xl2[s * F2 + c + 64];
        float p = lrelu(a0 + b0) * at0 + lrelu(a1 + b1v) * at1;
        #pragma unroll
        for (int o = 32; o; o >>= 1) p += __shfl_xor(p, o, 64);
        float w = 8.0f * __expf(p - sh);
        dnl += w;
        acc0 = fmaf(w, a0, acc0);
        acc1v = fmaf(w, a1, acc1v);
    }
    float dnf = 1.0f + dnl + 1e-16f;
    __shared__ float l[8][F2];
    l[wave][c]      = (x0 + acc0) / dnf;
    l[wave][c + 64] = (x1 + acc1v) / dnf;
    __syncthreads();
    if (t < F2) {
        float s = 0.f;
        #pragma unroll
        for (int w = 0; w < 8; ++w) s += l[w][t];
        atomicAdd(&out[t], s * (1.0f / NN));
    }
}

extern "C" void kernel_launch(void* const* d_in, const int* in_sizes, int n_in,
                              void* d_out, int out_size, void* d_ws, size_t ws_size,
                              hipStream_t stream) {
    const float* in   = (const float*)d_in[0];
    const int*   ei   = (const int*)d_in[1];
    const float* Wt   = (const float*)d_in[2];
    const float* bt   = (const float*)d_in[3];
    const float* Wl1  = (const float*)d_in[4];
    const float* Wr1  = (const float*)d_in[5];
    const float* att1 = (const float*)d_in[6];
    const float* b1   = (const float*)d_in[7];
    const float* Wl2  = (const float*)d_in[8];
    const float* Wr2  = (const float*)d_in[9];
    const float* att2 = (const float*)d_in[10];
    const float* b2   = (const float*)d_in[11];
    float* out = (float*)d_out;

    float* ws = (float*)d_ws;
    _Float16* xTh = (_Float16*)ws;               // N*128 f16
    _Float16* h1h = xTh + (size_t)N * 128;       // N*256 f16
    float* xl1  = (float*)(h1h + (size_t)N * F1); // NN*F1
    float* xr1  = xl1 + NN * F1;
    float* xl2  = xr1 + NN * F1;                 // NN*F2
    float* xr2  = xl2 + NN * F2;
    _Float16* Tt  = (_Float16*)(xr2 + NN * F2);  // 128*128
    _Float16* T1l = Tt + 128 * 128;              // 256*128
    _Float16* T1r = T1l + 256 * 128;
    _Float16* T2l = T1r + 256 * 128;             // 128*256
    _Float16* T2r = T2l + 128 * 256;
    int* cnt  = (int*)(T2r + 128 * 256);         // NN
    int* srcs = cnt + NN;                        // NN*MAXDEG

    k_prep<<<145, 256, 0, stream>>>(Wt, Wl1, Wr1, Wl2, Wr2, b2,
                                    Tt, T1l, T1r, T2l, T2r, cnt, out);
    k_cvt_scat<<<384, 256, 0, stream>>>(in, xTh, ei, cnt, srcs);
    k_gm1f<<<512, 512, 0, stream>>>(xTh, Tt, bt, T1l, T1r, b1, xl1, xr1, h1h);
    k_g1gm2<<<512, 512, 0, stream>>>(cnt, srcs, xl1, xr1, att1, b1, h1h,
                                     T2l, T2r, xl2, xr2, out);
    k_g2out<<<256, 512, 0, stream>>>(cnt, srcs, xl2, xr2, att2, out);
}

// Round 14
// 183.525 us; speedup vs baseline: 1.9757x; 1.0381x over previous
//
#include <hip/hip_runtime.h>
#include <hip/hip_bf16.h>
#include <math.h>

#define NEG_SLOPE 0.2f

constexpr int BSZ = 8, T = 100, NN = 2048, N = BSZ * NN; // N = 16384
constexpr int CIN = 128, F1 = 256, F2 = 128;
constexpr int E = 32768;
constexpr int KP = 40;      // padded LDS inner dim (f16) for 32-k tiles
constexpr int MAXDEG = 64;

typedef _Float16 f16x8 __attribute__((ext_vector_type(8)));
typedef float f32x4 __attribute__((ext_vector_type(4)));

__device__ inline float lrelu(float m) { return m > 0.f ? m : NEG_SLOPE * m; }
__device__ inline float eluf(float v) { return v > 0.f ? v : expm1f(v); }

// ===== D1: weight transposes (+f16, +K-pad) ; zero cnt ; out = b2 =====
__global__ __launch_bounds__(256) void k_prep(const float* __restrict__ Wt,
        const float* __restrict__ Wl1, const float* __restrict__ Wr1,
        const float* __restrict__ Wl2, const float* __restrict__ Wr2,
        const float* __restrict__ b2,
        _Float16* __restrict__ Tt, _Float16* __restrict__ T1l,
        _Float16* __restrict__ T1r, _Float16* __restrict__ T2l,
        _Float16* __restrict__ T2r, int* __restrict__ cnt, float* __restrict__ out) {
    const int job = blockIdx.x;
    const int t = threadIdx.x;
    if (job == 144) {
        for (int i = t; i < NN; i += 256) cnt[i] = 0;
        for (int i = t; i < BSZ * F2; i += 256) out[i] = b2[i & (F2 - 1)];
        return;
    }
    int which, base;
    if (job < 16)       { which = 0; base = 0; }
    else if (job < 48)  { which = 1; base = 16; }
    else if (job < 80)  { which = 2; base = 48; }
    else if (job < 112) { which = 3; base = 80; }
    else                { which = 4; base = 112; }
    const int Ks[5] = {100, 128, 128, 256, 256};
    const int Kd[5] = {128, 128, 128, 256, 256};
    const int Nc[5] = {128, 256, 256, 128, 128};
    const float* Wsrc[5] = {Wt, Wl1, Wr1, Wl2, Wr2};
    _Float16* Wdst[5] = {Tt, T1l, T1r, T2l, T2r};
    int rel = job - base;
    int ks = Ks[which], kd = Kd[which], nc = Nc[which];
    int tilesN = nc / 32;
    int tk = (rel / tilesN) * 32, tn = (rel % tilesN) * 32;
    const float* src = Wsrc[which];
    _Float16* dst = Wdst[which];
    __shared__ _Float16 tile[32][33];
    int tx = t & 31, ty = t >> 5;
    for (int r = ty; r < 32; r += 8)
        tile[r][tx] = (tk + r < ks) ? (_Float16)src[(tk + r) * nc + tn + tx] : (_Float16)0.f;
    __syncthreads();
    for (int r = ty; r < 32; r += 8)
        dst[(tn + r) * kd + tk + tx] = tile[tx][r];
}

// ===== D2: input transpose+f16 (blocks 0..255) ; hist + slot scatter (256..383) =====
__global__ __launch_bounds__(256) void k_cvt_scat(const float* __restrict__ in,
        _Float16* __restrict__ xTh, const int* __restrict__ ei,
        int* __restrict__ cnt, int* __restrict__ srcs) {
    const int t = threadIdx.x;
    const int blk = blockIdx.x;
    if (blk >= 256) {
        int i = (blk - 256) * 256 + t;          // 128 blocks x 256 = E
        int d = ei[E + i];
        int slot = atomicAdd(&cnt[d], 1);
        if (slot < MAXDEG) srcs[d * MAXDEG + slot] = ei[i];
        return;
    }
    __shared__ float lt[T * 65];
    const int b = blk >> 5, node0 = (blk & 31) * 64;
    for (int i = t; i < T * 64; i += 256) {
        int tt = i >> 6, n = i & 63;
        lt[tt * 65 + n] = in[(b * T + tt) * NN + node0 + n];
    }
    __syncthreads();
    const int node = t >> 2, seg = t & 3;
    _Float16* dst = &xTh[(size_t)(b * NN + node0 + node) * 128 + seg * 32];
    #pragma unroll
    for (int j = 0; j < 4; ++j) {
        f16x8 v;
        #pragma unroll
        for (int e = 0; e < 8; ++e) {
            int k = seg * 32 + j * 8 + e;
            v[e] = (k < T) ? (_Float16)lt[k * 65 + node] : (_Float16)0.f;
        }
        *(f16x8*)&dst[j * 8] = v;
    }
}

// ===== D3: fused temb GEMM (xh tile in LDS) + layer-1 dual GEMM =====
// rows<NN -> xl1/xr1 fp32; rows>=NN -> h1h = f16 elu(aL + b1)
__global__ __launch_bounds__(512) void k_gm1f(const _Float16* __restrict__ xTh,
        const _Float16* __restrict__ Tt, const float* __restrict__ bt,
        const _Float16* __restrict__ T1l, const _Float16* __restrict__ T1r,
        const float* __restrict__ b1,
        float* __restrict__ xl1, float* __restrict__ xr1, _Float16* __restrict__ h1h) {
    __shared__ __align__(16) char smem[8704 + 40960];
    _Float16* xt  = (_Float16*)smem;            // [32][136] f16 = 8704 B
    _Float16* stg = (_Float16*)(smem + 8704);   // staging, 40960 B
    const int t = threadIdx.x;
    const int wave = t >> 6, lane = t & 63;
    const int quad = lane >> 4, l15 = lane & 15;
    const int row0 = blockIdx.x * 32;
    // --- Phase A: temb GEMM, out tile -> LDS xt
    #pragma unroll
    for (int it = 0; it < 4; ++it) {            // stage Tt [128][128] -> [128][136]
        int idx = t + it * 512;
        int col = idx >> 4, j = idx & 15;
        *(f16x8*)&stg[col * 136 + j * 8] = *(const f16x8*)&Tt[col * 128 + j * 8];
    }
    __syncthreads();
    {
        const int wcol = wave * 16 + l15;       // 8 waves x 16 = 128 cols
        f32x4 a0 = {0,0,0,0}, a1 = {0,0,0,0};
        #pragma unroll
        for (int kt = 0; kt < 128; kt += 32) {
            f16x8 af0 = *(const f16x8*)&xTh[(size_t)(row0 + l15) * 128 + kt + quad * 8];
            f16x8 af1 = *(const f16x8*)&xTh[(size_t)(row0 + 16 + l15) * 128 + kt + quad * 8];
            f16x8 bf  = *(const f16x8*)&stg[wcol * 136 + kt + quad * 8];
            a0 = __builtin_amdgcn_mfma_f32_16x16x32_f16(af0, bf, a0, 0, 0, 0);
            a1 = __builtin_amdgcn_mfma_f32_16x16x32_f16(af1, bf, a1, 0, 0, 0);
        }
        float bv = bt[wcol];
        #pragma unroll
        for (int r = 0; r < 4; ++r) {
            xt[(quad * 4 + r) * 136 + wcol]      = (_Float16)(a0[r] + bv);
            xt[(16 + quad * 4 + r) * 136 + wcol] = (_Float16)(a1[r] + bv);
        }
    }
    __syncthreads();
    // --- Phase B: layer-1 dual GEMM, A from LDS xt
    const int mat = wave >> 2, cg4 = wave & 3;
    const int nmats = (row0 < NN) ? 2 : 1;
    f32x4 acc[2][4];
    #pragma unroll
    for (int s = 0; s < 2; ++s)
        #pragma unroll
        for (int c = 0; c < 4; ++c) acc[s][c] = (f32x4){0,0,0,0};
    for (int kt = 0; kt < CIN; kt += 32) {
        if (kt) __syncthreads();
        for (int it = 0; it < nmats * 2; ++it) {   // nmats x 256 cols x 4 chunks
            int idx = t + it * 512;
            int m = idx >> 10, rem = idx & 1023;
            int col = rem >> 2, j = rem & 3;
            const _Float16* src = (m ? T1r : T1l) + col * CIN + kt + j * 8;
            *(f16x8*)&stg[(m * 256 + col) * KP + j * 8] = *(const f16x8*)src;
        }
        __syncthreads();
        f16x8 af0 = *(const f16x8*)&xt[l15 * 136 + kt + quad * 8];
        f16x8 af1 = *(const f16x8*)&xt[(16 + l15) * 136 + kt + quad * 8];
        if (mat < nmats) {
            #pragma unroll
            for (int ct = 0; ct < 4; ++ct) {
                int col = cg4 * 64 + ct * 16 + l15;
                f16x8 bf = *(const f16x8*)&stg[(mat * 256 + col) * KP + quad * 8];
                acc[0][ct] = __builtin_amdgcn_mfma_f32_16x16x32_f16(af0, bf, acc[0][ct], 0, 0, 0);
                acc[1][ct] = __builtin_amdgcn_mfma_f32_16x16x32_f16(af1, bf, acc[1][ct], 0, 0, 0);
            }
        }
    }
    if (row0 < NN) {
        float* dst = mat ? xr1 : xl1;
        #pragma unroll
        for (int s = 0; s < 2; ++s)
            #pragma unroll
            for (int ct = 0; ct < 4; ++ct) {
                int col = cg4 * 64 + ct * 16 + l15;
                #pragma unroll
                for (int r = 0; r < 4; ++r)
                    dst[(row0 + s * 16 + quad * 4 + r) * F1 + col] = acc[s][ct][r];
            }
    } else if (mat == 0) {
        #pragma unroll
        for (int ct = 0; ct < 4; ++ct) {
            int col = cg4 * 64 + ct * 16 + l15;
            float bv = b1[col];
            #pragma unroll
            for (int s = 0; s < 2; ++s)
                #pragma unroll
                for (int r = 0; r < 4; ++r)
                    h1h[(size_t)(row0 + s * 16 + quad * 4 + r) * F1 + col] =
                        (_Float16)eluf(acc[s][ct][r] + bv);
        }
    }
}

// ===== D4: gather layer 1 (2048 blocks, 4 waves split edges) -> h1h f16 =====
__global__ __launch_bounds__(256) void k_gat1(const int* __restrict__ cnt,
        const int* __restrict__ srcs, const float* __restrict__ xl1,
        const float* __restrict__ xr1, const float* __restrict__ att1,
        const float* __restrict__ b1, _Float16* __restrict__ h1h) {
    const int d = blockIdx.x;
    const int t = threadIdx.x;
    const int wv = t >> 6, c = t & 63;
    int deg = cnt[d]; deg = deg < MAXDEG ? deg : MAXDEG;
    float b[4], at[4], sh[4], acc[4] = {0,0,0,0}, dnl[4] = {0,0,0,0};
    #pragma unroll
    for (int k = 0; k < 4; ++k) {
        b[k]  = xr1[d * F1 + c + 64 * k];
        at[k] = att1[c + 64 * k];
        sh[k] = lrelu(xl1[d * F1 + c + 64 * k] + b[k]) * at[k];
    }
    #pragma unroll
    for (int o = 32; o; o >>= 1) {
        #pragma unroll
        for (int k = 0; k < 4; ++k) sh[k] += __shfl_xor(sh[k], o, 64);
    }
    for (int e = wv; e < deg; e += 4) {
        int s = srcs[d * MAXDEG + e];
        float a[4], p[4];
        #pragma unroll
        for (int k = 0; k < 4; ++k) {
            a[k] = xl1[s * F1 + c + 64 * k];
            p[k] = lrelu(a[k] + b[k]) * at[k];
        }
        #pragma unroll
        for (int o = 32; o; o >>= 1) {
            #pragma unroll
            for (int k = 0; k < 4; ++k) p[k] += __shfl_xor(p[k], o, 64);
        }
        #pragma unroll
        for (int k = 0; k < 4; ++k) {
            float w = 8.0f * __expf(p[k] - sh[k]);
            dnl[k] += w;
            acc[k] = fmaf(w, a[k], acc[k]);
        }
    }
    __shared__ float lacc[4][F1];
    __shared__ float ldn[4][4];
    #pragma unroll
    for (int k = 0; k < 4; ++k) lacc[wv][c + 64 * k] = acc[k];
    if (c < 4) ldn[wv][c] = dnl[c];
    __syncthreads();
    int f = t, h = t >> 6;
    float tot = xl1[d * F1 + f] + lacc[0][f] + lacc[1][f] + lacc[2][f] + lacc[3][f];
    float dnf = 1.0f + ldn[0][h] + ldn[1][h] + ldn[2][h] + ldn[3][h];
    h1h[(size_t)d * F1 + f] = (_Float16)eluf(tot / (dnf + 1e-16f) + b1[f]);
}

// ===== D5: layer-2 dual GEMM, A from global h1h =====
// rows<NN -> xl2/xr2; rows>=NN -> fused batch-mean atomicAdd into out (batches 1..7)
__global__ __launch_bounds__(512) void k_gm2(const _Float16* __restrict__ h1h,
        const _Float16* __restrict__ T2l, const _Float16* __restrict__ T2r,
        float* __restrict__ xl2, float* __restrict__ xr2, float* __restrict__ out) {
    __shared__ __align__(16) _Float16 bs[2 * 128 * KP];  // 20 KB
    const int t = threadIdx.x;
    const int wave = t >> 6, lane = t & 63;
    const int quad = lane >> 4, l15 = lane & 15;
    const int mat = wave >> 2, cg4 = wave & 3;
    const int row0 = blockIdx.x * 32;
    const int nmats = (row0 < NN) ? 2 : 1;
    f32x4 acc[2][2];
    #pragma unroll
    for (int s = 0; s < 2; ++s)
        #pragma unroll
        for (int c = 0; c < 2; ++c) acc[s][c] = (f32x4){0,0,0,0};
    for (int kt = 0; kt < F1; kt += 32) {
        if (kt) __syncthreads();
        for (int it = 0; it < nmats; ++it) {
            int idx = t + it * 512;
            int m = idx >> 9, rem = idx & 511;
            int col = rem >> 2, j = rem & 3;
            const _Float16* src = (m ? T2r : T2l) + col * F1 + kt + j * 8;
            *(f16x8*)&bs[(m * 128 + col) * KP + j * 8] = *(const f16x8*)src;
        }
        __syncthreads();
        if (mat < nmats) {
            f16x8 af0 = *(const f16x8*)&h1h[(size_t)(row0 + l15) * F1 + kt + quad * 8];
            f16x8 af1 = *(const f16x8*)&h1h[(size_t)(row0 + 16 + l15) * F1 + kt + quad * 8];
            #pragma unroll
            for (int ct = 0; ct < 2; ++ct) {
                int col = cg4 * 32 + ct * 16 + l15;
                f16x8 bf = *(const f16x8*)&bs[(mat * 128 + col) * KP + quad * 8];
                acc[0][ct] = __builtin_amdgcn_mfma_f32_16x16x32_f16(af0, bf, acc[0][ct], 0, 0, 0);
                acc[1][ct] = __builtin_amdgcn_mfma_f32_16x16x32_f16(af1, bf, acc[1][ct], 0, 0, 0);
            }
        }
    }
    if (row0 < NN) {
        float* dst = mat ? xr2 : xl2;
        #pragma unroll
        for (int s = 0; s < 2; ++s)
            #pragma unroll
            for (int ct = 0; ct < 2; ++ct) {
                int col = cg4 * 32 + ct * 16 + l15;
                #pragma unroll
                for (int r = 0; r < 4; ++r)
                    dst[(row0 + s * 16 + quad * 4 + r) * F2 + col] = acc[s][ct][r];
            }
    } else if (mat == 0) {
        // self rows: final value (dn=1); fused batch-mean accumulation
        int b = row0 >> 11;
        #pragma unroll
        for (int ct = 0; ct < 2; ++ct) {
            float s8 = 0.f;
            #pragma unroll
            for (int s = 0; s < 2; ++s)
                #pragma unroll
                for (int r = 0; r < 4; ++r) s8 += acc[s][ct][r];
            s8 += __shfl_xor(s8, 16, 64);
            s8 += __shfl_xor(s8, 32, 64);
            if (quad == 0)
                atomicAdd(&out[b * F2 + cg4 * 32 + ct * 16 + l15], s8 * (1.0f / NN));
        }
    }
}

// ===== D6: gather layer 2 (2048 blocks, 4 waves split edges) + fused batch-0 mean =====
__global__ __launch_bounds__(256) void k_gat2out(const int* __restrict__ cnt,
        const int* __restrict__ srcs, const float* __restrict__ xl2,
        const float* __restrict__ xr2, const float* __restrict__ att2,
        float* __restrict__ out) {
    const int d = blockIdx.x;
    const int t = threadIdx.x;
    const int wv = t >> 6, c = t & 63;
    int deg = cnt[d]; deg = deg < MAXDEG ? deg : MAXDEG;
    float b0 = xr2[d * F2 + c], b1v = xr2[d * F2 + c + 64];
    float at0 = att2[c], at1 = att2[c + 64];
    float sh = lrelu(xl2[d * F2 + c] + b0) * at0 + lrelu(xl2[d * F2 + c + 64] + b1v) * at1;
    #pragma unroll
    for (int o = 32; o; o >>= 1) sh += __shfl_xor(sh, o, 64);
    float acc0 = 0.f, acc1v = 0.f, dnl = 0.f;
    for (int e = wv; e < deg; e += 4) {
        int s = srcs[d * MAXDEG + e];
        float a0 = xl2[s * F2 + c], a1 = xl2[s * F2 + c + 64];
        float p = lrelu(a0 + b0) * at0 + lrelu(a1 + b1v) * at1;
        #pragma unroll
        for (int o = 32; o; o >>= 1) p += __shfl_xor(p, o, 64);
        float w = 8.0f * __expf(p - sh);
        dnl += w;
        acc0 = fmaf(w, a0, acc0);
        acc1v = fmaf(w, a1, acc1v);
    }
    __shared__ float lacc[4][F2];
    __shared__ float ldn[4];
    lacc[wv][c] = acc0;
    lacc[wv][c + 64] = acc1v;
    if (c == 0) ldn[wv] = dnl;
    __syncthreads();
    if (t < F2) {
        int f = t;
        float dnf = 1.0f + ldn[0] + ldn[1] + ldn[2] + ldn[3] + 1e-16f;
        float val = (xl2[d * F2 + f] + lacc[0][f] + lacc[1][f] + lacc[2][f] + lacc[3][f]) / dnf;
        atomicAdd(&out[f], val * (1.0f / NN));   // batch 0
    }
}

extern "C" void kernel_launch(void* const* d_in, const int* in_sizes, int n_in,
                              void* d_out, int out_size, void* d_ws, size_t ws_size,
                              hipStream_t stream) {
    const float* in   = (const float*)d_in[0];
    const int*   ei   = (const int*)d_in[1];
    const float* Wt   = (const float*)d_in[2];
    const float* bt   = (const float*)d_in[3];
    const float* Wl1  = (const float*)d_in[4];
    const float* Wr1  = (const float*)d_in[5];
    const float* att1 = (const float*)d_in[6];
    const float* b1   = (const float*)d_in[7];
    const float* Wl2  = (const float*)d_in[8];
    const float* Wr2  = (const float*)d_in[9];
    const float* att2 = (const float*)d_in[10];
    const float* b2   = (const float*)d_in[11];
    float* out = (float*)d_out;

    float* ws = (float*)d_ws;
    _Float16* xTh = (_Float16*)ws;               // N*128 f16
    _Float16* h1h = xTh + (size_t)N * 128;       // N*256 f16
    float* xl1  = (float*)(h1h + (size_t)N * F1); // NN*F1
    float* xr1  = xl1 + NN * F1;
    float* xl2  = xr1 + NN * F1;                 // NN*F2
    float* xr2  = xl2 + NN * F2;
    _Float16* Tt  = (_Float16*)(xr2 + NN * F2);  // 128*128
    _Float16* T1l = Tt + 128 * 128;              // 256*128
    _Float16* T1r = T1l + 256 * 128;
    _Float16* T2l = T1r + 256 * 128;             // 128*256
    _Float16* T2r = T2l + 128 * 256;
    int* cnt  = (int*)(T2r + 128 * 256);         // NN
    int* srcs = cnt + NN;                        // NN*MAXDEG

    k_prep<<<145, 256, 0, stream>>>(Wt, Wl1, Wr1, Wl2, Wr2, b2,
                                    Tt, T1l, T1r, T2l, T2r, cnt, out);
    k_cvt_scat<<<384, 256, 0, stream>>>(in, xTh, ei, cnt, srcs);
    k_gm1f<<<512, 512, 0, stream>>>(xTh, Tt, bt, T1l, T1r, b1, xl1, xr1, h1h);
    k_gat1<<<NN, 256, 0, stream>>>(cnt, srcs, xl1, xr1, att1, b1, h1h);
    k_gm2<<<512, 512, 0, stream>>>(h1h, T2l, T2r, xl2, xr2, out);
    k_gat2out<<<NN, 256, 0, stream>>>(cnt, srcs, xl2, xr2, att2, out);
}

// Round 15
// 141.775 us; speedup vs baseline: 2.5575x; 1.2945x over previous
//
#include <hip/hip_runtime.h>
#include <hip/hip_bf16.h>
#include <math.h>

#define NEG_SLOPE 0.2f

constexpr int BSZ = 8, T = 100, NN = 2048, N = BSZ * NN; // N = 16384
constexpr int CIN = 128, F1 = 256, F2 = 128;
constexpr int E = 32768;
constexpr int KP = 40;      // padded LDS inner dim (f16) for 32-k tiles
constexpr int MAXDEG = 64;

typedef _Float16 f16x8 __attribute__((ext_vector_type(8)));
typedef float f32x4 __attribute__((ext_vector_type(4)));

__device__ inline float lrelu(float m) { return m > 0.f ? m : NEG_SLOPE * m; }
__device__ inline float eluf(float v) { return v > 0.f ? v : expm1f(v); }

// ===== D1: weight transposes (+f16, +K-pad) ; zero cnt ; out = b2 =====
__global__ __launch_bounds__(256) void k_prep(const float* __restrict__ Wt,
        const float* __restrict__ Wl1, const float* __restrict__ Wr1,
        const float* __restrict__ Wl2, const float* __restrict__ Wr2,
        const float* __restrict__ b2,
        _Float16* __restrict__ Tt, _Float16* __restrict__ T1l,
        _Float16* __restrict__ T1r, _Float16* __restrict__ T2l,
        _Float16* __restrict__ T2r, int* __restrict__ cnt, float* __restrict__ out) {
    const int job = blockIdx.x;
    const int t = threadIdx.x;
    if (job == 144) {
        for (int i = t; i < NN; i += 256) cnt[i] = 0;
        for (int i = t; i < BSZ * F2; i += 256) out[i] = b2[i & (F2 - 1)];
        return;
    }
    int which, base;
    if (job < 16)       { which = 0; base = 0; }
    else if (job < 48)  { which = 1; base = 16; }
    else if (job < 80)  { which = 2; base = 48; }
    else if (job < 112) { which = 3; base = 80; }
    else                { which = 4; base = 112; }
    const int Ks[5] = {100, 128, 128, 256, 256};
    const int Kd[5] = {128, 128, 128, 256, 256};
    const int Nc[5] = {128, 256, 256, 128, 128};
    const float* Wsrc[5] = {Wt, Wl1, Wr1, Wl2, Wr2};
    _Float16* Wdst[5] = {Tt, T1l, T1r, T2l, T2r};
    int rel = job - base;
    int ks = Ks[which], kd = Kd[which], nc = Nc[which];
    int tilesN = nc / 32;
    int tk = (rel / tilesN) * 32, tn = (rel % tilesN) * 32;
    const float* src = Wsrc[which];
    _Float16* dst = Wdst[which];
    __shared__ _Float16 tile[32][33];
    int tx = t & 31, ty = t >> 5;
    for (int r = ty; r < 32; r += 8)
        tile[r][tx] = (tk + r < ks) ? (_Float16)src[(tk + r) * nc + tn + tx] : (_Float16)0.f;
    __syncthreads();
    for (int r = ty; r < 32; r += 8)
        dst[(tn + r) * kd + tk + tx] = tile[tx][r];
}

// ===== D2: input transpose+f16 (blocks 0..255) ; hist + slot scatter (256..383) =====
__global__ __launch_bounds__(256) void k_cvt_scat(const float* __restrict__ in,
        _Float16* __restrict__ xTh, const int* __restrict__ ei,
        int* __restrict__ cnt, int* __restrict__ srcs) {
    const int t = threadIdx.x;
    const int blk = blockIdx.x;
    if (blk >= 256) {
        int i = (blk - 256) * 256 + t;          // 128 blocks x 256 = E
        int d = ei[E + i];
        int slot = atomicAdd(&cnt[d], 1);
        if (slot < MAXDEG) srcs[d * MAXDEG + slot] = ei[i];
        return;
    }
    __shared__ float lt[T * 65];
    const int b = blk >> 5, node0 = (blk & 31) * 64;
    for (int i = t; i < T * 64; i += 256) {
        int tt = i >> 6, n = i & 63;
        lt[tt * 65 + n] = in[(b * T + tt) * NN + node0 + n];
    }
    __syncthreads();
    const int node = t >> 2, seg = t & 3;
    _Float16* dst = &xTh[(size_t)(b * NN + node0 + node) * 128 + seg * 32];
    #pragma unroll
    for (int j = 0; j < 4; ++j) {
        f16x8 v;
        #pragma unroll
        for (int e = 0; e < 8; ++e) {
            int k = seg * 32 + j * 8 + e;
            v[e] = (k < T) ? (_Float16)lt[k * 65 + node] : (_Float16)0.f;
        }
        *(f16x8*)&dst[j * 8] = v;
    }
}

// ===== D3: fused temb GEMM (xh tile in LDS) + layer-1 dual GEMM =====
// rows<NN -> xl1/xr1 fp32; rows>=NN -> h1h = f16 elu(aL + b1)
__global__ __launch_bounds__(512) void k_gm1f(const _Float16* __restrict__ xTh,
        const _Float16* __restrict__ Tt, const float* __restrict__ bt,
        const _Float16* __restrict__ T1l, const _Float16* __restrict__ T1r,
        const float* __restrict__ b1,
        float* __restrict__ xl1, float* __restrict__ xr1, _Float16* __restrict__ h1h) {
    __shared__ __align__(16) char smem[8704 + 40960];
    _Float16* xt  = (_Float16*)smem;            // [32][136] f16 = 8704 B
    _Float16* stg = (_Float16*)(smem + 8704);   // staging, 40960 B
    const int t = threadIdx.x;
    const int wave = t >> 6, lane = t & 63;
    const int quad = lane >> 4, l15 = lane & 15;
    const int row0 = blockIdx.x * 32;
    // --- Phase A: temb GEMM, out tile -> LDS xt
    #pragma unroll
    for (int it = 0; it < 4; ++it) {            // stage Tt [128][128] -> [128][136]
        int idx = t + it * 512;
        int col = idx >> 4, j = idx & 15;
        *(f16x8*)&stg[col * 136 + j * 8] = *(const f16x8*)&Tt[col * 128 + j * 8];
    }
    __syncthreads();
    {
        const int wcol = wave * 16 + l15;       // 8 waves x 16 = 128 cols
        f32x4 a0 = {0,0,0,0}, a1 = {0,0,0,0};
        #pragma unroll
        for (int kt = 0; kt < 128; kt += 32) {
            f16x8 af0 = *(const f16x8*)&xTh[(size_t)(row0 + l15) * 128 + kt + quad * 8];
            f16x8 af1 = *(const f16x8*)&xTh[(size_t)(row0 + 16 + l15) * 128 + kt + quad * 8];
            f16x8 bf  = *(const f16x8*)&stg[wcol * 136 + kt + quad * 8];
            a0 = __builtin_amdgcn_mfma_f32_16x16x32_f16(af0, bf, a0, 0, 0, 0);
            a1 = __builtin_amdgcn_mfma_f32_16x16x32_f16(af1, bf, a1, 0, 0, 0);
        }
        float bv = bt[wcol];
        #pragma unroll
        for (int r = 0; r < 4; ++r) {
            xt[(quad * 4 + r) * 136 + wcol]      = (_Float16)(a0[r] + bv);
            xt[(16 + quad * 4 + r) * 136 + wcol] = (_Float16)(a1[r] + bv);
        }
    }
    __syncthreads();
    // --- Phase B: layer-1 dual GEMM, A from LDS xt
    const int mat = wave >> 2, cg4 = wave & 3;
    const int nmats = (row0 < NN) ? 2 : 1;
    f32x4 acc[2][4];
    #pragma unroll
    for (int s = 0; s < 2; ++s)
        #pragma unroll
        for (int c = 0; c < 4; ++c) acc[s][c] = (f32x4){0,0,0,0};
    for (int kt = 0; kt < CIN; kt += 32) {
        if (kt) __syncthreads();
        for (int it = 0; it < nmats * 2; ++it) {   // nmats x 256 cols x 4 chunks
            int idx = t + it * 512;
            int m = idx >> 10, rem = idx & 1023;
            int col = rem >> 2, j = rem & 3;
            const _Float16* src = (m ? T1r : T1l) + col * CIN + kt + j * 8;
            *(f16x8*)&stg[(m * 256 + col) * KP + j * 8] = *(const f16x8*)src;
        }
        __syncthreads();
        f16x8 af0 = *(const f16x8*)&xt[l15 * 136 + kt + quad * 8];
        f16x8 af1 = *(const f16x8*)&xt[(16 + l15) * 136 + kt + quad * 8];
        if (mat < nmats) {
            #pragma unroll
            for (int ct = 0; ct < 4; ++ct) {
                int col = cg4 * 64 + ct * 16 + l15;
                f16x8 bf = *(const f16x8*)&stg[(mat * 256 + col) * KP + quad * 8];
                acc[0][ct] = __builtin_amdgcn_mfma_f32_16x16x32_f16(af0, bf, acc[0][ct], 0, 0, 0);
                acc[1][ct] = __builtin_amdgcn_mfma_f32_16x16x32_f16(af1, bf, acc[1][ct], 0, 0, 0);
            }
        }
    }
    if (row0 < NN) {
        float* dst = mat ? xr1 : xl1;
        #pragma unroll
        for (int s = 0; s < 2; ++s)
            #pragma unroll
            for (int ct = 0; ct < 4; ++ct) {
                int col = cg4 * 64 + ct * 16 + l15;
                #pragma unroll
                for (int r = 0; r < 4; ++r)
                    dst[(row0 + s * 16 + quad * 4 + r) * F1 + col] = acc[s][ct][r];
            }
    } else if (mat == 0) {
        #pragma unroll
        for (int ct = 0; ct < 4; ++ct) {
            int col = cg4 * 64 + ct * 16 + l15;
            float bv = b1[col];
            #pragma unroll
            for (int s = 0; s < 2; ++s)
                #pragma unroll
                for (int r = 0; r < 4; ++r)
                    h1h[(size_t)(row0 + s * 16 + quad * 4 + r) * F1 + col] =
                        (_Float16)eluf(acc[s][ct][r] + bv);
        }
    }
}

// ===== D4: gather layer 1 (2048 blocks, 4 waves split edges) -> h1h f16 =====
__global__ __launch_bounds__(256) void k_gat1(const int* __restrict__ cnt,
        const int* __restrict__ srcs, const float* __restrict__ xl1,
        const float* __restrict__ xr1, const float* __restrict__ att1,
        const float* __restrict__ b1, _Float16* __restrict__ h1h) {
    const int d = blockIdx.x;
    const int t = threadIdx.x;
    const int wv = t >> 6, c = t & 63;
    int deg = cnt[d]; deg = deg < MAXDEG ? deg : MAXDEG;
    float b[4], at[4], sh[4], acc[4] = {0,0,0,0}, dnl[4] = {0,0,0,0};
    #pragma unroll
    for (int k = 0; k < 4; ++k) {
        b[k]  = xr1[d * F1 + c + 64 * k];
        at[k] = att1[c + 64 * k];
        sh[k] = lrelu(xl1[d * F1 + c + 64 * k] + b[k]) * at[k];
    }
    #pragma unroll
    for (int o = 32; o; o >>= 1) {
        #pragma unroll
        for (int k = 0; k < 4; ++k) sh[k] += __shfl_xor(sh[k], o, 64);
    }
    for (int e = wv; e < deg; e += 4) {
        int s = srcs[d * MAXDEG + e];
        float a[4], p[4];
        #pragma unroll
        for (int k = 0; k < 4; ++k) {
            a[k] = xl1[s * F1 + c + 64 * k];
            p[k] = lrelu(a[k] + b[k]) * at[k];
        }
        #pragma unroll
        for (int o = 32; o; o >>= 1) {
            #pragma unroll
            for (int k = 0; k < 4; ++k) p[k] += __shfl_xor(p[k], o, 64);
        }
        #pragma unroll
        for (int k = 0; k < 4; ++k) {
            float w = 8.0f * __expf(p[k] - sh[k]);
            dnl[k] += w;
            acc[k] = fmaf(w, a[k], acc[k]);
        }
    }
    __shared__ float lacc[4][F1];
    __shared__ float ldn[4][4];
    #pragma unroll
    for (int k = 0; k < 4; ++k) lacc[wv][c + 64 * k] = acc[k];
    if (c < 4) ldn[wv][c] = dnl[c];
    __syncthreads();
    int f = t, h = t >> 6;
    float tot = xl1[d * F1 + f] + lacc[0][f] + lacc[1][f] + lacc[2][f] + lacc[3][f];
    float dnf = 1.0f + ldn[0][h] + ldn[1][h] + ldn[2][h] + ldn[3][h];
    h1h[(size_t)d * F1 + f] = (_Float16)eluf(tot / (dnf + 1e-16f) + b1[f]);
}

// ===== D5: layer-2 dual GEMM, A from global h1h =====
// rows<NN -> xl2/xr2; rows>=NN -> fused batch-mean atomicAdd into out (batches 1..7)
__global__ __launch_bounds__(512) void k_gm2(const _Float16* __restrict__ h1h,
        const _Float16* __restrict__ T2l, const _Float16* __restrict__ T2r,
        float* __restrict__ xl2, float* __restrict__ xr2, float* __restrict__ out) {
    __shared__ __align__(16) _Float16 bs[2 * 128 * KP];  // 20 KB
    const int t = threadIdx.x;
    const int wave = t >> 6, lane = t & 63;
    const int quad = lane >> 4, l15 = lane & 15;
    const int mat = wave >> 2, cg4 = wave & 3;
    const int row0 = blockIdx.x * 32;
    const int nmats = (row0 < NN) ? 2 : 1;
    f32x4 acc[2][2];
    #pragma unroll
    for (int s = 0; s < 2; ++s)
        #pragma unroll
        for (int c = 0; c < 2; ++c) acc[s][c] = (f32x4){0,0,0,0};
    for (int kt = 0; kt < F1; kt += 32) {
        if (kt) __syncthreads();
        for (int it = 0; it < nmats; ++it) {
            int idx = t + it * 512;
            int m = idx >> 9, rem = idx & 511;
            int col = rem >> 2, j = rem & 3;
            const _Float16* src = (m ? T2r : T2l) + col * F1 + kt + j * 8;
            *(f16x8*)&bs[(m * 128 + col) * KP + j * 8] = *(const f16x8*)src;
        }
        __syncthreads();
        if (mat < nmats) {
            f16x8 af0 = *(const f16x8*)&h1h[(size_t)(row0 + l15) * F1 + kt + quad * 8];
            f16x8 af1 = *(const f16x8*)&h1h[(size_t)(row0 + 16 + l15) * F1 + kt + quad * 8];
            #pragma unroll
            for (int ct = 0; ct < 2; ++ct) {
                int col = cg4 * 32 + ct * 16 + l15;
                f16x8 bf = *(const f16x8*)&bs[(mat * 128 + col) * KP + quad * 8];
                acc[0][ct] = __builtin_amdgcn_mfma_f32_16x16x32_f16(af0, bf, acc[0][ct], 0, 0, 0);
                acc[1][ct] = __builtin_amdgcn_mfma_f32_16x16x32_f16(af1, bf, acc[1][ct], 0, 0, 0);
            }
        }
    }
    if (row0 < NN) {
        float* dst = mat ? xr2 : xl2;
        #pragma unroll
        for (int s = 0; s < 2; ++s)
            #pragma unroll
            for (int ct = 0; ct < 2; ++ct) {
                int col = cg4 * 32 + ct * 16 + l15;
                #pragma unroll
                for (int r = 0; r < 4; ++r)
                    dst[(row0 + s * 16 + quad * 4 + r) * F2 + col] = acc[s][ct][r];
            }
    } else if (mat == 0) {
        // self rows: final value (dn=1); fused batch-mean accumulation (64 atomics/address)
        int b = row0 >> 11;
        #pragma unroll
        for (int ct = 0; ct < 2; ++ct) {
            float s8 = 0.f;
            #pragma unroll
            for (int s = 0; s < 2; ++s)
                #pragma unroll
                for (int r = 0; r < 4; ++r) s8 += acc[s][ct][r];
            s8 += __shfl_xor(s8, 16, 64);
            s8 += __shfl_xor(s8, 32, 64);
            if (quad == 0)
                atomicAdd(&out[b * F2 + cg4 * 32 + ct * 16 + l15], s8 * (1.0f / NN));
        }
    }
}

// ===== D6: gather layer 2 (2048 blocks, 4 waves split edges) -> acc2 plain stores =====
__global__ __launch_bounds__(256) void k_gat2(const int* __restrict__ cnt,
        const int* __restrict__ srcs, const float* __restrict__ xl2,
        const float* __restrict__ xr2, const float* __restrict__ att2,
        float* __restrict__ acc2) {
    const int d = blockIdx.x;
    const int t = threadIdx.x;
    const int wv = t >> 6, c = t & 63;
    int deg = cnt[d]; deg = deg < MAXDEG ? deg : MAXDEG;
    float b0 = xr2[d * F2 + c], b1v = xr2[d * F2 + c + 64];
    float at0 = att2[c], at1 = att2[c + 64];
    float sh = lrelu(xl2[d * F2 + c] + b0) * at0 + lrelu(xl2[d * F2 + c + 64] + b1v) * at1;
    #pragma unroll
    for (int o = 32; o; o >>= 1) sh += __shfl_xor(sh, o, 64);
    float acc0 = 0.f, acc1v = 0.f, dnl = 0.f;
    for (int e = wv; e < deg; e += 4) {
        int s = srcs[d * MAXDEG + e];
        float a0 = xl2[s * F2 + c], a1 = xl2[s * F2 + c + 64];
        float p = lrelu(a0 + b0) * at0 + lrelu(a1 + b1v) * at1;
        #pragma unroll
        for (int o = 32; o; o >>= 1) p += __shfl_xor(p, o, 64);
        float w = 8.0f * __expf(p - sh);
        dnl += w;
        acc0 = fmaf(w, a0, acc0);
        acc1v = fmaf(w, a1, acc1v);
    }
    __shared__ float lacc[4][F2];
    __shared__ float ldn[4];
    lacc[wv][c] = acc0;
    lacc[wv][c + 64] = acc1v;
    if (c == 0) ldn[wv] = dnl;
    __syncthreads();
    if (t < F2) {
        int f = t;
        float dnf = 1.0f + ldn[0] + ldn[1] + ldn[2] + ldn[3] + 1e-16f;
        acc2[d * F2 + f] =
            (xl2[d * F2 + f] + lacc[0][f] + lacc[1][f] + lacc[2][f] + lacc[3][f]) / dnf;
    }
}

// ===== D7: batch-0 mean: 32 chunks x 64 nodes, 32 atomics/address =====
__global__ __launch_bounds__(128) void k_out0(const float* __restrict__ acc2,
        float* __restrict__ out) {
    int chunk = blockIdx.x;
    int c = threadIdx.x;
    float s = 0.f;
    int n0 = chunk * 64;
    for (int i = 0; i < 64; ++i)
        s += acc2[(n0 + i) * F2 + c];
    atomicAdd(&out[c], s * (1.0f / NN));
}

extern "C" void kernel_launch(void* const* d_in, const int* in_sizes, int n_in,
                              void* d_out, int out_size, void* d_ws, size_t ws_size,
                              hipStream_t stream) {
    const float* in   = (const float*)d_in[0];
    const int*   ei   = (const int*)d_in[1];
    const float* Wt   = (const float*)d_in[2];
    const float* bt   = (const float*)d_in[3];
    const float* Wl1  = (const float*)d_in[4];
    const float* Wr1  = (const float*)d_in[5];
    const float* att1 = (const float*)d_in[6];
    const float* b1   = (const float*)d_in[7];
    const float* Wl2  = (const float*)d_in[8];
    const float* Wr2  = (const float*)d_in[9];
    const float* att2 = (const float*)d_in[10];
    const float* b2   = (const float*)d_in[11];
    float* out = (float*)d_out;

    float* ws = (float*)d_ws;
    _Float16* xTh = (_Float16*)ws;               // N*128 f16
    _Float16* h1h = xTh + (size_t)N * 128;       // N*256 f16
    float* xl1  = (float*)(h1h + (size_t)N * F1); // NN*F1
    float* xr1  = xl1 + NN * F1;
    float* xl2  = xr1 + NN * F1;                 // NN*F2
    float* xr2  = xl2 + NN * F2;
    float* acc2 = xr2 + NN * F2;                 // NN*F2
    _Float16* Tt  = (_Float16*)(acc2 + NN * F2); // 128*128
    _Float16* T1l = Tt + 128 * 128;              // 256*128
    _Float16* T1r = T1l + 256 * 128;
    _Float16* T2l = T1r + 256 * 128;             // 128*256
    _Float16* T2r = T2l + 128 * 256;
    int* cnt  = (int*)(T2r + 128 * 256);         // NN
    int* srcs = cnt + NN;                        // NN*MAXDEG

    k_prep<<<145, 256, 0, stream>>>(Wt, Wl1, Wr1, Wl2, Wr2, b2,
                                    Tt, T1l, T1r, T2l, T2r, cnt, out);
    k_cvt_scat<<<384, 256, 0, stream>>>(in, xTh, ei, cnt, srcs);
    k_gm1f<<<512, 512, 0, stream>>>(xTh, Tt, bt, T1l, T1r, b1, xl1, xr1, h1h);
    k_gat1<<<NN, 256, 0, stream>>>(cnt, srcs, xl1, xr1, att1, b1, h1h);
    k_gm2<<<512, 512, 0, stream>>>(h1h, T2l, T2r, xl2, xr2, out);
    k_gat2<<<NN, 256, 0, stream>>>(cnt, srcs, xl2, xr2, att2, acc2);
    k_out0<<<32, 128, 0, stream>>>(acc2, out);
}

// Round 16
// 138.893 us; speedup vs baseline: 2.6105x; 1.0207x over previous
//
#include <hip/hip_runtime.h>
#include <hip/hip_bf16.h>
#include <math.h>

#define NEG_SLOPE 0.2f

constexpr int BSZ = 8, T = 100, NN = 2048, N = BSZ * NN; // N = 16384
constexpr int CIN = 128, F1 = 256, F2 = 128;
constexpr int E = 32768;
constexpr int KP = 40;      // padded LDS inner dim (f16) for 32-k tiles
constexpr int MAXDEG = 64;

typedef _Float16 f16x8 __attribute__((ext_vector_type(8)));
typedef float f32x4 __attribute__((ext_vector_type(4)));

__device__ inline float lrelu(float m) { return m > 0.f ? m : NEG_SLOPE * m; }
__device__ inline float eluf(float v) { return v > 0.f ? v : expm1f(v); }

// ===== D1: weight transposes + zero cnt + out=b2 (jobs 0..144) ; input cvt (145..400) =====
__global__ __launch_bounds__(256) void k_prep_cvt(const float* __restrict__ in,
        const float* __restrict__ Wt,
        const float* __restrict__ Wl1, const float* __restrict__ Wr1,
        const float* __restrict__ Wl2, const float* __restrict__ Wr2,
        const float* __restrict__ b2,
        _Float16* __restrict__ Tt, _Float16* __restrict__ T1l,
        _Float16* __restrict__ T1r, _Float16* __restrict__ T2l,
        _Float16* __restrict__ T2r, int* __restrict__ cnt, float* __restrict__ out,
        _Float16* __restrict__ xTh) {
    __shared__ __align__(16) char smem[26016];
    const int job = blockIdx.x;
    const int t = threadIdx.x;
    if (job < 145) {
        if (job == 144) {
            for (int i = t; i < NN; i += 256) cnt[i] = 0;
            for (int i = t; i < BSZ * F2; i += 256) out[i] = b2[i & (F2 - 1)];
            return;
        }
        int which, base;
        if (job < 16)       { which = 0; base = 0; }
        else if (job < 48)  { which = 1; base = 16; }
        else if (job < 80)  { which = 2; base = 48; }
        else if (job < 112) { which = 3; base = 80; }
        else                { which = 4; base = 112; }
        const int Ks[5] = {100, 128, 128, 256, 256};
        const int Kd[5] = {128, 128, 128, 256, 256};
        const int Nc[5] = {128, 256, 256, 128, 128};
        const float* Wsrc[5] = {Wt, Wl1, Wr1, Wl2, Wr2};
        _Float16* Wdst[5] = {Tt, T1l, T1r, T2l, T2r};
        int rel = job - base;
        int ks = Ks[which], kd = Kd[which], nc = Nc[which];
        int tilesN = nc / 32;
        int tk = (rel / tilesN) * 32, tn = (rel % tilesN) * 32;
        const float* src = Wsrc[which];
        _Float16* dst = Wdst[which];
        _Float16 (*tile)[33] = (_Float16(*)[33])smem;
        int tx = t & 31, ty = t >> 5;
        for (int r = ty; r < 32; r += 8)
            tile[r][tx] = (tk + r < ks) ? (_Float16)src[(tk + r) * nc + tn + tx] : (_Float16)0.f;
        __syncthreads();
        for (int r = ty; r < 32; r += 8)
            dst[(tn + r) * kd + tk + tx] = tile[tx][r];
        return;
    }
    // input transpose+f16
    float* lt = (float*)smem;                  // T*65*4 = 26000 B
    const int blk = job - 145;
    const int b = blk >> 5, node0 = (blk & 31) * 64;
    for (int i = t; i < T * 64; i += 256) {
        int tt = i >> 6, n = i & 63;
        lt[tt * 65 + n] = in[(b * T + tt) * NN + node0 + n];
    }
    __syncthreads();
    const int node = t >> 2, seg = t & 3;
    _Float16* dst = &xTh[(size_t)(b * NN + node0 + node) * 128 + seg * 32];
    #pragma unroll
    for (int j = 0; j < 4; ++j) {
        f16x8 v;
        #pragma unroll
        for (int e = 0; e < 8; ++e) {
            int k = seg * 32 + j * 8 + e;
            v[e] = (k < T) ? (_Float16)lt[k * 65 + node] : (_Float16)0.f;
        }
        *(f16x8*)&dst[j * 8] = v;
    }
}

// ===== D2: fused temb+layer-1 GEMM (blocks 0..511) ; edge slot scatter (512..575) =====
__global__ __launch_bounds__(512) void k_gm1f_scat(const _Float16* __restrict__ xTh,
        const _Float16* __restrict__ Tt, const float* __restrict__ bt,
        const _Float16* __restrict__ T1l, const _Float16* __restrict__ T1r,
        const float* __restrict__ b1, const int* __restrict__ ei,
        int* __restrict__ cnt, int* __restrict__ srcs,
        float* __restrict__ xl1, float* __restrict__ xr1, _Float16* __restrict__ h1h) {
    const int t = threadIdx.x;
    if (blockIdx.x >= 512) {                   // scatter: cnt zeroed in D1
        int i = (blockIdx.x - 512) * 512 + t;  // 64 x 512 = E
        int d = ei[E + i];
        int slot = atomicAdd(&cnt[d], 1);
        if (slot < MAXDEG) srcs[d * MAXDEG + slot] = ei[i];
        return;
    }
    __shared__ __align__(16) char smem[8704 + 40960];
    _Float16* xt  = (_Float16*)smem;           // [32][136] f16
    _Float16* stg = (_Float16*)(smem + 8704);  // staging
    const int wave = t >> 6, lane = t & 63;
    const int quad = lane >> 4, l15 = lane & 15;
    const int row0 = blockIdx.x * 32;
    // --- Phase A: temb GEMM, out tile -> LDS xt
    #pragma unroll
    for (int it = 0; it < 4; ++it) {           // stage Tt [128][128] -> [128][136]
        int idx = t + it * 512;
        int col = idx >> 4, j = idx & 15;
        *(f16x8*)&stg[col * 136 + j * 8] = *(const f16x8*)&Tt[col * 128 + j * 8];
    }
    __syncthreads();
    {
        const int wcol = wave * 16 + l15;      // 8 waves x 16 = 128 cols
        f32x4 a0 = {0,0,0,0}, a1 = {0,0,0,0};
        #pragma unroll
        for (int kt = 0; kt < 128; kt += 32) {
            f16x8 af0 = *(const f16x8*)&xTh[(size_t)(row0 + l15) * 128 + kt + quad * 8];
            f16x8 af1 = *(const f16x8*)&xTh[(size_t)(row0 + 16 + l15) * 128 + kt + quad * 8];
            f16x8 bf  = *(const f16x8*)&stg[wcol * 136 + kt + quad * 8];
            a0 = __builtin_amdgcn_mfma_f32_16x16x32_f16(af0, bf, a0, 0, 0, 0);
            a1 = __builtin_amdgcn_mfma_f32_16x16x32_f16(af1, bf, a1, 0, 0, 0);
        }
        float bv = bt[wcol];
        #pragma unroll
        for (int r = 0; r < 4; ++r) {
            xt[(quad * 4 + r) * 136 + wcol]      = (_Float16)(a0[r] + bv);
            xt[(16 + quad * 4 + r) * 136 + wcol] = (_Float16)(a1[r] + bv);
        }
    }
    __syncthreads();
    // --- Phase B: layer-1 dual GEMM, A from LDS xt
    const int mat = wave >> 2, cg4 = wave & 3;
    const int nmats = (row0 < NN) ? 2 : 1;
    f32x4 acc[2][4];
    #pragma unroll
    for (int s = 0; s < 2; ++s)
        #pragma unroll
        for (int c = 0; c < 4; ++c) acc[s][c] = (f32x4){0,0,0,0};
    for (int kt = 0; kt < CIN; kt += 32) {
        if (kt) __syncthreads();
        for (int it = 0; it < nmats * 2; ++it) {   // nmats x 256 cols x 4 chunks
            int idx = t + it * 512;
            int m = idx >> 10, rem = idx & 1023;
            int col = rem >> 2, j = rem & 3;
            const _Float16* src = (m ? T1r : T1l) + col * CIN + kt + j * 8;
            *(f16x8*)&stg[(m * 256 + col) * KP + j * 8] = *(const f16x8*)src;
        }
        __syncthreads();
        f16x8 af0 = *(const f16x8*)&xt[l15 * 136 + kt + quad * 8];
        f16x8 af1 = *(const f16x8*)&xt[(16 + l15) * 136 + kt + quad * 8];
        if (mat < nmats) {
            #pragma unroll
            for (int ct = 0; ct < 4; ++ct) {
                int col = cg4 * 64 + ct * 16 + l15;
                f16x8 bf = *(const f16x8*)&stg[(mat * 256 + col) * KP + quad * 8];
                acc[0][ct] = __builtin_amdgcn_mfma_f32_16x16x32_f16(af0, bf, acc[0][ct], 0, 0, 0);
                acc[1][ct] = __builtin_amdgcn_mfma_f32_16x16x32_f16(af1, bf, acc[1][ct], 0, 0, 0);
            }
        }
    }
    if (row0 < NN) {
        float* dst = mat ? xr1 : xl1;
        #pragma unroll
        for (int s = 0; s < 2; ++s)
            #pragma unroll
            for (int ct = 0; ct < 4; ++ct) {
                int col = cg4 * 64 + ct * 16 + l15;
                #pragma unroll
                for (int r = 0; r < 4; ++r)
                    dst[(row0 + s * 16 + quad * 4 + r) * F1 + col] = acc[s][ct][r];
            }
    } else if (mat == 0) {
        #pragma unroll
        for (int ct = 0; ct < 4; ++ct) {
            int col = cg4 * 64 + ct * 16 + l15;
            float bv = b1[col];
            #pragma unroll
            for (int s = 0; s < 2; ++s)
                #pragma unroll
                for (int r = 0; r < 4; ++r)
                    h1h[(size_t)(row0 + s * 16 + quad * 4 + r) * F1 + col] =
                        (_Float16)eluf(acc[s][ct][r] + bv);
        }
    }
}

// ===== D3: gather layer 1 (blocks 0..2047) ; layer-2 GEMM self rows (2048..2495) =====
// gm2-self depends only on h1h rows>=NN (from D2), so it overlaps the gathers.
__global__ __launch_bounds__(256) void k_gat1_gm2s(const int* __restrict__ cnt,
        const int* __restrict__ srcs, const float* __restrict__ xl1,
        const float* __restrict__ xr1, const float* __restrict__ att1,
        const float* __restrict__ b1, _Float16* __restrict__ h1h,
        const _Float16* __restrict__ T2l, float* __restrict__ out) {
    __shared__ __align__(16) char smem[10304];
    const int t = threadIdx.x;
    const int wave = t >> 6, lane = t & 63;
    if (blockIdx.x >= 2048) {
        // --- gm2 self rows: 448 blocks x 32 rows, Wl only, fused batch-mean
        _Float16* bs = (_Float16*)smem;        // 128*KP f16 = 10240 B
        const int quad = lane >> 4, l15 = lane & 15;
        const int row0 = NN + (blockIdx.x - 2048) * 32;
        f32x4 acc[2][2];
        #pragma unroll
        for (int s = 0; s < 2; ++s)
            #pragma unroll
            for (int c = 0; c < 2; ++c) acc[s][c] = (f32x4){0,0,0,0};
        for (int kt = 0; kt < F1; kt += 32) {
            if (kt) __syncthreads();
            #pragma unroll
            for (int it = 0; it < 2; ++it) {   // 128 cols x 4 chunks = 512 items
                int idx = t + it * 256;
                int col = idx >> 2, j = idx & 3;
                *(f16x8*)&bs[col * KP + j * 8] = *(const f16x8*)&T2l[col * F1 + kt + j * 8];
            }
            __syncthreads();
            f16x8 af0 = *(const f16x8*)&h1h[(size_t)(row0 + l15) * F1 + kt + quad * 8];
            f16x8 af1 = *(const f16x8*)&h1h[(size_t)(row0 + 16 + l15) * F1 + kt + quad * 8];
            #pragma unroll
            for (int ct = 0; ct < 2; ++ct) {
                int col = wave * 32 + ct * 16 + l15;
                f16x8 bf = *(const f16x8*)&bs[col * KP + quad * 8];
                acc[0][ct] = __builtin_amdgcn_mfma_f32_16x16x32_f16(af0, bf, acc[0][ct], 0, 0, 0);
                acc[1][ct] = __builtin_amdgcn_mfma_f32_16x16x32_f16(af1, bf, acc[1][ct], 0, 0, 0);
            }
        }
        int b = row0 >> 11;                    // batches 1..7; 64 atomics/address
        #pragma unroll
        for (int ct = 0; ct < 2; ++ct) {
            float s8 = 0.f;
            #pragma unroll
            for (int s = 0; s < 2; ++s)
                #pragma unroll
                for (int r = 0; r < 4; ++r) s8 += acc[s][ct][r];
            s8 += __shfl_xor(s8, 16, 64);
            s8 += __shfl_xor(s8, 32, 64);
            if (quad == 0)
                atomicAdd(&out[b * F2 + wave * 32 + ct * 16 + l15], s8 * (1.0f / NN));
        }
        return;
    }
    // --- gather layer 1 (4 waves split edges) -> h1h f16
    const int d = blockIdx.x;
    const int wv = wave, c = lane;
    int deg = cnt[d]; deg = deg < MAXDEG ? deg : MAXDEG;
    float b[4], at[4], sh[4], acc[4] = {0,0,0,0}, dnl[4] = {0,0,0,0};
    #pragma unroll
    for (int k = 0; k < 4; ++k) {
        b[k]  = xr1[d * F1 + c + 64 * k];
        at[k] = att1[c + 64 * k];
        sh[k] = lrelu(xl1[d * F1 + c + 64 * k] + b[k]) * at[k];
    }
    #pragma unroll
    for (int o = 32; o; o >>= 1) {
        #pragma unroll
        for (int k = 0; k < 4; ++k) sh[k] += __shfl_xor(sh[k], o, 64);
    }
    for (int e = wv; e < deg; e += 4) {
        int s = srcs[d * MAXDEG + e];
        float a[4], p[4];
        #pragma unroll
        for (int k = 0; k < 4; ++k) {
            a[k] = xl1[s * F1 + c + 64 * k];
            p[k] = lrelu(a[k] + b[k]) * at[k];
        }
        #pragma unroll
        for (int o = 32; o; o >>= 1) {
            #pragma unroll
            for (int k = 0; k < 4; ++k) p[k] += __shfl_xor(p[k], o, 64);
        }
        #pragma unroll
        for (int k = 0; k < 4; ++k) {
            float w = 8.0f * __expf(p[k] - sh[k]);
            dnl[k] += w;
            acc[k] = fmaf(w, a[k], acc[k]);
        }
    }
    float (*lacc)[F1] = (float(*)[F1])smem;          // 4*256*4 = 4096 B
    float (*ldn)[4]   = (float(*)[4])(smem + 4096);  // 64 B
    #pragma unroll
    for (int k = 0; k < 4; ++k) lacc[wv][c + 64 * k] = acc[k];
    if (c < 4) ldn[wv][c] = dnl[c];
    __syncthreads();
    int f = t, h = t >> 6;
    float tot = xl1[d * F1 + f] + lacc[0][f] + lacc[1][f] + lacc[2][f] + lacc[3][f];
    float dnf = 1.0f + ldn[0][h] + ldn[1][h] + ldn[2][h] + ldn[3][h];
    h1h[(size_t)d * F1 + f] = (_Float16)eluf(tot / (dnf + 1e-16f) + b1[f]);
}

// ===== D4: layer-2 dual GEMM, local rows only (64 blocks) =====
__global__ __launch_bounds__(512) void k_gm2loc(const _Float16* __restrict__ h1h,
        const _Float16* __restrict__ T2l, const _Float16* __restrict__ T2r,
        float* __restrict__ xl2, float* __restrict__ xr2) {
    __shared__ __align__(16) _Float16 bs[2 * 128 * KP];  // 20 KB
    const int t = threadIdx.x;
    const int wave = t >> 6, lane = t & 63;
    const int quad = lane >> 4, l15 = lane & 15;
    const int mat = wave >> 2, cg4 = wave & 3;
    const int row0 = blockIdx.x * 32;
    f32x4 acc[2][2];
    #pragma unroll
    for (int s = 0; s < 2; ++s)
        #pragma unroll
        for (int c = 0; c < 2; ++c) acc[s][c] = (f32x4){0,0,0,0};
    for (int kt = 0; kt < F1; kt += 32) {
        if (kt) __syncthreads();
        #pragma unroll
        for (int it = 0; it < 2; ++it) {
            int idx = t + it * 512;
            int m = idx >> 9, rem = idx & 511;
            int col = rem >> 2, j = rem & 3;
            const _Float16* src = (m ? T2r : T2l) + col * F1 + kt + j * 8;
            *(f16x8*)&bs[(m * 128 + col) * KP + j * 8] = *(const f16x8*)src;
        }
        __syncthreads();
        f16x8 af0 = *(const f16x8*)&h1h[(size_t)(row0 + l15) * F1 + kt + quad * 8];
        f16x8 af1 = *(const f16x8*)&h1h[(size_t)(row0 + 16 + l15) * F1 + kt + quad * 8];
        #pragma unroll
        for (int ct = 0; ct < 2; ++ct) {
            int col = cg4 * 32 + ct * 16 + l15;
            f16x8 bf = *(const f16x8*)&bs[(mat * 128 + col) * KP + quad * 8];
            acc[0][ct] = __builtin_amdgcn_mfma_f32_16x16x32_f16(af0, bf, acc[0][ct], 0, 0, 0);
            acc[1][ct] = __builtin_amdgcn_mfma_f32_16x16x32_f16(af1, bf, acc[1][ct], 0, 0, 0);
        }
    }
    float* dst = mat ? xr2 : xl2;
    #pragma unroll
    for (int s = 0; s < 2; ++s)
        #pragma unroll
        for (int ct = 0; ct < 2; ++ct) {
            int col = cg4 * 32 + ct * 16 + l15;
            #pragma unroll
            for (int r = 0; r < 4; ++r)
                dst[(row0 + s * 16 + quad * 4 + r) * F2 + col] = acc[s][ct][r];
        }
}

// ===== D5: gather layer 2 (2048 blocks) -> acc2 plain stores =====
__global__ __launch_bounds__(256) void k_gat2(const int* __restrict__ cnt,
        const int* __restrict__ srcs, const float* __restrict__ xl2,
        const float* __restrict__ xr2, const float* __restrict__ att2,
        float* __restrict__ acc2) {
    const int d = blockIdx.x;
    const int t = threadIdx.x;
    const int wv = t >> 6, c = t & 63;
    int deg = cnt[d]; deg = deg < MAXDEG ? deg : MAXDEG;
    float b0 = xr2[d * F2 + c], b1v = xr2[d * F2 + c + 64];
    float at0 = att2[c], at1 = att2[c + 64];
    float sh = lrelu(xl2[d * F2 + c] + b0) * at0 + lrelu(xl2[d * F2 + c + 64] + b1v) * at1;
    #pragma unroll
    for (int o = 32; o; o >>= 1) sh += __shfl_xor(sh, o, 64);
    float acc0 = 0.f, acc1v = 0.f, dnl = 0.f;
    for (int e = wv; e < deg; e += 4) {
        int s = srcs[d * MAXDEG + e];
        float a0 = xl2[s * F2 + c], a1 = xl2[s * F2 + c + 64];
        float p = lrelu(a0 + b0) * at0 + lrelu(a1 + b1v) * at1;
        #pragma unroll
        for (int o = 32; o; o >>= 1) p += __shfl_xor(p, o, 64);
        float w = 8.0f * __expf(p - sh);
        dnl += w;
        acc0 = fmaf(w, a0, acc0);
        acc1v = fmaf(w, a1, acc1v);
    }
    __shared__ float lacc[4][F2];
    __shared__ float ldn[4];
    lacc[wv][c] = acc0;
    lacc[wv][c + 64] = acc1v;
    if (c == 0) ldn[wv] = dnl;
    __syncthreads();
    if (t < F2) {
        int f = t;
        float dnf = 1.0f + ldn[0] + ldn[1] + ldn[2] + ldn[3] + 1e-16f;
        acc2[d * F2 + f] =
            (xl2[d * F2 + f] + lacc[0][f] + lacc[1][f] + lacc[2][f] + lacc[3][f]) / dnf;
    }
}

// ===== D6: batch-0 mean: 32 chunks x 64 nodes, 32 atomics/address =====
__global__ __launch_bounds__(128) void k_out0(const float* __restrict__ acc2,
        float* __restrict__ out) {
    int chunk = blockIdx.x;
    int c = threadIdx.x;
    float s = 0.f;
    int n0 = chunk * 64;
    for (int i = 0; i < 64; ++i)
        s += acc2[(n0 + i) * F2 + c];
    atomicAdd(&out[c], s * (1.0f / NN));
}

extern "C" void kernel_launch(void* const* d_in, const int* in_sizes, int n_in,
                              void* d_out, int out_size, void* d_ws, size_t ws_size,
                              hipStream_t stream) {
    const float* in   = (const float*)d_in[0];
    const int*   ei   = (const int*)d_in[1];
    const float* Wt   = (const float*)d_in[2];
    const float* bt   = (const float*)d_in[3];
    const float* Wl1  = (const float*)d_in[4];
    const float* Wr1  = (const float*)d_in[5];
    const float* att1 = (const float*)d_in[6];
    const float* b1   = (const float*)d_in[7];
    const float* Wl2  = (const float*)d_in[8];
    const float* Wr2  = (const float*)d_in[9];
    const float* att2 = (const float*)d_in[10];
    const float* b2   = (const float*)d_in[11];
    float* out = (float*)d_out;

    float* ws = (float*)d_ws;
    _Float16* xTh = (_Float16*)ws;               // N*128 f16
    _Float16* h1h = xTh + (size_t)N * 128;       // N*256 f16
    float* xl1  = (float*)(h1h + (size_t)N * F1); // NN*F1
    float* xr1  = xl1 + NN * F1;
    float* xl2  = xr1 + NN * F1;                 // NN*F2
    float* xr2  = xl2 + NN * F2;
    float* acc2 = xr2 + NN * F2;                 // NN*F2
    _Float16* Tt  = (_Float16*)(acc2 + NN * F2); // 128*128
    _Float16* T1l = Tt + 128 * 128;              // 256*128
    _Float16* T1r = T1l + 256 * 128;
    _Float16* T2l = T1r + 256 * 128;             // 128*256
    _Float16* T2r = T2l + 128 * 256;
    int* cnt  = (int*)(T2r + 128 * 256);         // NN
    int* srcs = cnt + NN;                        // NN*MAXDEG

    k_prep_cvt<<<401, 256, 0, stream>>>(in, Wt, Wl1, Wr1, Wl2, Wr2, b2,
                                        Tt, T1l, T1r, T2l, T2r, cnt, out, xTh);
    k_gm1f_scat<<<576, 512, 0, stream>>>(xTh, Tt, bt, T1l, T1r, b1, ei, cnt, srcs,
                                         xl1, xr1, h1h);
    k_gat1_gm2s<<<2496, 256, 0, stream>>>(cnt, srcs, xl1, xr1, att1, b1, h1h, T2l, out);
    k_gm2loc<<<64, 512, 0, stream>>>(h1h, T2l, T2r, xl2, xr2);
    k_gat2<<<NN, 256, 0, stream>>>(cnt, srcs, xl2, xr2, att2, acc2);
    k_out0<<<32, 128, 0, stream>>>(acc2, out);
}